// Round 3
// baseline (1291.306 us; speedup 1.0000x reference)
//
#include <hip/hip_runtime.h>

#define EDIM 64
#define SCAN_BLK 256
#define SCAN_CHUNK 2048  // 8 elements per thread

// ---------------------------------------------------------------------------
// CSR/CSC build: histogram -> hierarchical exclusive scan -> cursor scatter.
// ---------------------------------------------------------------------------
__global__ __launch_bounds__(256) void hist_kernel(
    const int* __restrict__ rows, const int* __restrict__ cols,
    int* __restrict__ cntU, int* __restrict__ cntP, int nnz) {
  const int stride = gridDim.x * blockDim.x;
  for (int i = blockIdx.x * blockDim.x + threadIdx.x; i < nnz; i += stride) {
    atomicAdd(&cntU[rows[i]], 1);
    atomicAdd(&cntP[cols[i]], 1);
  }
}

__global__ __launch_bounds__(SCAN_BLK) void scan_reduce_kernel(
    const int* __restrict__ cnt, int n, int* __restrict__ bsum) {
  __shared__ int wsh[SCAN_BLK / 64];
  const int lane = threadIdx.x & 63, wid = threadIdx.x >> 6;
  const int base = blockIdx.x * SCAN_CHUNK + threadIdx.x * 8;
  int s = 0;
#pragma unroll
  for (int k = 0; k < 8; ++k) {
    const int idx = base + k;
    if (idx < n) s += cnt[idx];
  }
  for (int d = 32; d; d >>= 1) s += __shfl_down(s, d);
  if (lane == 0) wsh[wid] = s;
  __syncthreads();
  if (threadIdx.x == 0) {
    int t = 0;
    for (int w = 0; w < SCAN_BLK / 64; ++w) t += wsh[w];
    bsum[blockIdx.x] = t;
  }
}

__global__ void scan_top_kernel(int* __restrict__ bsum, int nb) {
  __shared__ int tmp[256];
  if ((int)threadIdx.x < nb) tmp[threadIdx.x] = bsum[threadIdx.x];
  __syncthreads();
  if (threadIdx.x == 0) {
    int run = 0;
    for (int i = 0; i < nb; ++i) { const int c = tmp[i]; tmp[i] = run; run += c; }
  }
  __syncthreads();
  if ((int)threadIdx.x < nb) bsum[threadIdx.x] = tmp[threadIdx.x];
}

__global__ __launch_bounds__(SCAN_BLK) void scan_apply_kernel(
    int* __restrict__ ptr, int n, const int* __restrict__ bsum) {
  __shared__ int wsum[SCAN_BLK / 64];
  const int lane = threadIdx.x & 63, wid = threadIdx.x >> 6;
  const int base = blockIdx.x * SCAN_CHUNK + threadIdx.x * 8;
  int v[8];
  int tot = 0;
#pragma unroll
  for (int k = 0; k < 8; ++k) {
    const int idx = base + k;
    v[k] = (idx < n) ? ptr[idx] : 0;
    tot += v[k];
  }
  int sc = tot;  // inclusive wave scan
  for (int d = 1; d < 64; d <<= 1) {
    const int o = __shfl_up(sc, d);
    if (lane >= d) sc += o;
  }
  if (lane == 63) wsum[wid] = sc;
  __syncthreads();
  int woff = 0;
  for (int w = 0; w < wid; ++w) woff += wsum[w];
  int run = bsum[blockIdx.x] + woff + sc - tot;  // exclusive offset
#pragma unroll
  for (int k = 0; k < 8; ++k) {
    const int idx = base + k;
    if (idx < n) ptr[idx] = run;
    run += v[k];
  }
}

__global__ __launch_bounds__(256) void scatter_kernel(
    const int* __restrict__ rows, const int* __restrict__ cols,
    int* __restrict__ ptrU, int* __restrict__ ptrP,
    int* __restrict__ permU, int* __restrict__ permP, int nnz) {
  const int stride = gridDim.x * blockDim.x;
  for (int i = blockIdx.x * blockDim.x + threadIdx.x; i < nnz; i += stride) {
    const int pu = atomicAdd(&ptrU[rows[i]], 1);
    permU[pu] = i;
    const int pp = atomicAdd(&ptrP[cols[i]], 1);
    permP[pp] = i;
  }
}

// ---------------------------------------------------------------------------
// Per-user gather, float4-vectorized, 4 nnz per step.
// lane = (sub = lane>>4, d4 = lane&15); lane handles dims d4*4..d4*4+3 for
// nnz with index%4==sub. Cross-sub reduce via shfl_xor(16,32) per user.
// No LDS -> full occupancy.
// ---------------------------------------------------------------------------
__global__ __launch_bounds__(256) void user_gather_kernel(
    const int* __restrict__ ptrU, const int* __restrict__ permU,
    const int* __restrict__ cols, const float* __restrict__ vals,
    const float* __restrict__ geo, const float* __restrict__ seq,
    const float* __restrict__ colp,
    float* __restrict__ gw, float* __restrict__ sw, float* __restrict__ pw,
    int U) {
  const int lane = threadIdx.x & 63;
  const int sub = lane >> 4, d4 = lane & 15;
  const int wv = blockIdx.x * 4 + (threadIdx.x >> 6);
  const int nW = gridDim.x * 4;
  for (int u = wv; u < U; u += nW) {
    const int start = (u == 0) ? 0 : ptrU[u - 1];
    const int end = ptrU[u];
    float4 g4 = {0, 0, 0, 0}, s4 = {0, 0, 0, 0}, p4 = {0, 0, 0, 0};
    for (int k0 = start; k0 < end; k0 += 64) {
      int c_v = 0;
      float v_v = 0.f;
      const int kk = k0 + lane;
      if (kk < end) {
        const int id = permU[kk];
        c_v = cols[id];
        v_v = vals[id];
      }
      const int steps = (min(64, end - k0) + 3) >> 2;
      for (int t = 0; t < steps; ++t) {
        const int src = t * 4 + sub;
        const int cc = __shfl(c_v, src);
        const float vv = __shfl(v_v, src);
        const float4* gp = (const float4*)(geo + (size_t)cc * EDIM);
        const float4* sp = (const float4*)(seq + (size_t)cc * EDIM);
        const float4* pp = (const float4*)(colp + (size_t)cc * EDIM);
        const float4 a = gp[d4], bb = sp[d4], c = pp[d4];
        g4.x += vv * a.x;  g4.y += vv * a.y;  g4.z += vv * a.z;  g4.w += vv * a.w;
        s4.x += vv * bb.x; s4.y += vv * bb.y; s4.z += vv * bb.z; s4.w += vv * bb.w;
        p4.x += vv * c.x;  p4.y += vv * c.y;  p4.z += vv * c.z;  p4.w += vv * c.w;
      }
    }
#pragma unroll
    for (int m = 16; m <= 32; m <<= 1) {
      g4.x += __shfl_xor(g4.x, m); g4.y += __shfl_xor(g4.y, m);
      g4.z += __shfl_xor(g4.z, m); g4.w += __shfl_xor(g4.w, m);
      s4.x += __shfl_xor(s4.x, m); s4.y += __shfl_xor(s4.y, m);
      s4.z += __shfl_xor(s4.z, m); s4.w += __shfl_xor(s4.w, m);
      p4.x += __shfl_xor(p4.x, m); p4.y += __shfl_xor(p4.y, m);
      p4.z += __shfl_xor(p4.z, m); p4.w += __shfl_xor(p4.w, m);
    }
    if (sub == 0) {
      ((float4*)(gw + (size_t)u * EDIM))[d4] = g4;
      ((float4*)(sw + (size_t)u * EDIM))[d4] = s4;
      ((float4*)(pw + (size_t)u * EDIM))[d4] = p4;
    }
  }
}

// ---------------------------------------------------------------------------
// Fusion: msg @ W^T + bias + gated merge. W^T in LDS padded to stride 65
// (conflict-free writes AND reads). hg written in-place over ga.
// ---------------------------------------------------------------------------
#define FBLK 1024
__global__ __launch_bounds__(FBLK) void fusion_kernel(
    const float* __restrict__ ga, const float* __restrict__ sa,
    const float* __restrict__ pa, const float* __restrict__ uemb,
    const float* __restrict__ W, const float* __restrict__ b,
    float* __restrict__ hg, int U) {
  extern __shared__ float wt[];  // [448][65]
  for (int idx = threadIdx.x; idx < 448 * 64; idx += FBLK) {
    const int e = idx / 448;
    const int f = idx - e * 448;
    wt[f * 65 + e] = W[idx];
  }
  __syncthreads();
  const int lane = threadIdx.x & 63;
  const int wv = blockIdx.x * (FBLK / 64) + (threadIdx.x >> 6);
  const int nW = gridDim.x * (FBLK / 64);
  const float bias = b[lane];

  for (int u0 = wv * 4; u0 < U; u0 += nW * 4) {
    const int cnt = min(4, U - u0);
    float g[4], s[4], p[4], acc[4];
#pragma unroll
    for (int i = 0; i < 4; ++i) {
      const int u = u0 + (i < cnt ? i : 0);
      const size_t off = (size_t)u * EDIM + lane;
      g[i] = ga[off]; s[i] = sa[off]; p[i] = pa[off];
      acc[i] = 0.f;
    }
    for (int j = 0; j < 64; ++j) {
      const int basej = j * 65 + lane;
      const float w0 = wt[basej];
      const float w1 = wt[basej + 64 * 65];
      const float w2 = wt[basej + 128 * 65];
      const float w3 = wt[basej + 192 * 65];
      const float w4 = wt[basej + 256 * 65];
      const float w5 = wt[basej + 320 * 65];
      const float w6 = wt[basej + 384 * 65];
#pragma unroll
      for (int i = 0; i < 4; ++i) {
        const float gj = __shfl(g[i], j);
        const float sj = __shfl(s[i], j);
        const float pj = __shfl(p[i], j);
        const float gs = gj * sj, gp = gj * pj, sp = sj * pj;
        acc[i] += w0 * gj + w1 * sj + w2 * pj + w3 * gs + w4 * gp + w5 * sp +
                  w6 * gs * pj;
      }
    }
#pragma unroll
    for (int i = 0; i < 4; ++i) {
      if (i < cnt) {
        const float me = acc[i] + bias;
        const size_t off = (size_t)(u0 + i) * EDIM + lane;
        const float ue = uemb[off];
        hg[off] = me + ue + me * ue;
      }
    }
  }
}

// ---------------------------------------------------------------------------
// Per-POI gather (transpose side), float4-vectorized, fused with mean:
// out = init + (L/2)*acc.
// ---------------------------------------------------------------------------
__global__ __launch_bounds__(256) void poi_gather_kernel(
    const int* __restrict__ ptrP, const int* __restrict__ permP,
    const int* __restrict__ rows, const float* __restrict__ pu_vals,
    const float* __restrict__ hg, const float* __restrict__ init,
    const int* __restrict__ num_layers, float* __restrict__ out, int P) {
  const float scale = 0.5f * (float)num_layers[0];
  const int lane = threadIdx.x & 63;
  const int sub = lane >> 4, d4 = lane & 15;
  const int wv = blockIdx.x * 4 + (threadIdx.x >> 6);
  const int nW = gridDim.x * 4;
  for (int c = wv; c < P; c += nW) {
    const int start = (c == 0) ? 0 : ptrP[c - 1];
    const int end = ptrP[c];
    float4 a4 = {0, 0, 0, 0};
    for (int k0 = start; k0 < end; k0 += 64) {
      int r_v = 0;
      float v_v = 0.f;
      const int kk = k0 + lane;
      if (kk < end) {
        const int id = permP[kk];
        r_v = rows[id];
        v_v = pu_vals[id];
      }
      const int steps = (min(64, end - k0) + 3) >> 2;
      for (int t = 0; t < steps; ++t) {
        const int src = t * 4 + sub;
        const int rr = __shfl(r_v, src);
        const float vv = __shfl(v_v, src);
        const float4 h = ((const float4*)(hg + (size_t)rr * EDIM))[d4];
        a4.x += vv * h.x; a4.y += vv * h.y; a4.z += vv * h.z; a4.w += vv * h.w;
      }
    }
#pragma unroll
    for (int m = 16; m <= 32; m <<= 1) {
      a4.x += __shfl_xor(a4.x, m); a4.y += __shfl_xor(a4.y, m);
      a4.z += __shfl_xor(a4.z, m); a4.w += __shfl_xor(a4.w, m);
    }
    if (sub == 0) {
      const float4 iv = ((const float4*)(init + (size_t)c * EDIM))[d4];
      float4 o;
      o.x = iv.x + scale * a4.x;
      o.y = iv.y + scale * a4.y;
      o.z = iv.z + scale * a4.z;
      o.w = iv.w + scale * a4.w;
      ((float4*)(out + (size_t)c * EDIM))[d4] = o;
    }
  }
}

extern "C" void kernel_launch(void* const* d_in, const int* in_sizes, int n_in,
                              void* d_out, int out_size, void* d_ws,
                              size_t ws_size, hipStream_t stream) {
  const float* init = (const float*)d_in[0];
  const float* colp = (const float*)d_in[1];
  const float* geo = (const float*)d_in[2];
  const float* seq = (const float*)d_in[3];
  const float* uemb = (const float*)d_in[4];
  const int* up_rows = (const int*)d_in[5];
  const int* up_cols = (const int*)d_in[6];
  const float* up_vals = (const float*)d_in[7];
  const float* pu_vals = (const float*)d_in[8];
  const float* W = (const float*)d_in[9];
  const float* b = (const float*)d_in[10];
  const int* num_layers = (const int*)d_in[11];

  const int U = in_sizes[4] / EDIM;
  const int P = in_sizes[0] / EDIM;
  const int NNZ = in_sizes[5];

  int* ptrU = (int*)d_ws;        // U
  int* ptrP = ptrU + U;          // P
  int* permU = ptrP + P;         // NNZ
  int* permP = permU + NNZ;      // NNZ
  int* bsumU = permP + NNZ;      // 256
  int* bsumP = bsumU + 256;      // 256
  float* ga = (float*)(bsumP + 256);  // U*64 (hg aliases this)
  float* sa = ga + (size_t)U * EDIM;
  float* pa = sa + (size_t)U * EDIM;
  float* hg = ga;  // in-place overwrite in fusion_kernel
  float* out = (float*)d_out;

  const int nbU = (U + SCAN_CHUNK - 1) / SCAN_CHUNK;
  const int nbP = (P + SCAN_CHUNK - 1) / SCAN_CHUNK;

  hipMemsetAsync(ptrU, 0, (size_t)(U + P) * sizeof(int), stream);

  hist_kernel<<<1024, 256, 0, stream>>>(up_rows, up_cols, ptrU, ptrP, NNZ);

  scan_reduce_kernel<<<nbU, SCAN_BLK, 0, stream>>>(ptrU, U, bsumU);
  scan_reduce_kernel<<<nbP, SCAN_BLK, 0, stream>>>(ptrP, P, bsumP);
  scan_top_kernel<<<1, 256, 0, stream>>>(bsumU, nbU);
  scan_top_kernel<<<1, 256, 0, stream>>>(bsumP, nbP);
  scan_apply_kernel<<<nbU, SCAN_BLK, 0, stream>>>(ptrU, U, bsumU);
  scan_apply_kernel<<<nbP, SCAN_BLK, 0, stream>>>(ptrP, P, bsumP);

  scatter_kernel<<<1024, 256, 0, stream>>>(up_rows, up_cols, ptrU, ptrP,
                                           permU, permP, NNZ);

  user_gather_kernel<<<2048, 256, 0, stream>>>(ptrU, permU, up_cols, up_vals,
                                               geo, seq, colp, ga, sa, pa, U);

  fusion_kernel<<<256, FBLK, 448 * 65 * sizeof(float), stream>>>(
      ga, sa, pa, uemb, W, b, hg, U);

  poi_gather_kernel<<<2048, 256, 0, stream>>>(ptrP, permP, up_rows, pu_vals,
                                              hg, init, num_layers, out, P);
}

// Round 4
// 1205.769 us; speedup vs baseline: 1.0709x; 1.0709x over previous
//
#include <hip/hip_runtime.h>

#define EDIM 64
#define SCAN_BLK 256
#define SCAN_CHUNK 2048  // 8 elements per thread

// ---------------------------------------------------------------------------
// Histogram (int4-vectorized, fire-and-forget atomics).
// ---------------------------------------------------------------------------
__global__ __launch_bounds__(256) void hist_kernel(
    const int* __restrict__ rows, const int* __restrict__ cols,
    int* __restrict__ cntU, int* __restrict__ cntP, int nnz) {
  const int t = blockIdx.x * blockDim.x + threadIdx.x;
  const int i0 = t * 4;
  if (i0 + 3 < nnz) {
    const int4 r = ((const int4*)rows)[t];
    const int4 c = ((const int4*)cols)[t];
    atomicAdd(&cntU[r.x], 1); atomicAdd(&cntU[r.y], 1);
    atomicAdd(&cntU[r.z], 1); atomicAdd(&cntU[r.w], 1);
    atomicAdd(&cntP[c.x], 1); atomicAdd(&cntP[c.y], 1);
    atomicAdd(&cntP[c.z], 1); atomicAdd(&cntP[c.w], 1);
  } else {
    for (int i = i0; i < nnz; ++i) {
      atomicAdd(&cntU[rows[i]], 1);
      atomicAdd(&cntP[cols[i]], 1);
    }
  }
}

// ---------------------------------------------------------------------------
// Hierarchical exclusive scan (unchanged).
// ---------------------------------------------------------------------------
__global__ __launch_bounds__(SCAN_BLK) void scan_reduce_kernel(
    const int* __restrict__ cnt, int n, int* __restrict__ bsum) {
  __shared__ int wsh[SCAN_BLK / 64];
  const int lane = threadIdx.x & 63, wid = threadIdx.x >> 6;
  const int base = blockIdx.x * SCAN_CHUNK + threadIdx.x * 8;
  int s = 0;
#pragma unroll
  for (int k = 0; k < 8; ++k) {
    const int idx = base + k;
    if (idx < n) s += cnt[idx];
  }
  for (int d = 32; d; d >>= 1) s += __shfl_down(s, d);
  if (lane == 0) wsh[wid] = s;
  __syncthreads();
  if (threadIdx.x == 0) {
    int t = 0;
    for (int w = 0; w < SCAN_BLK / 64; ++w) t += wsh[w];
    bsum[blockIdx.x] = t;
  }
}

__global__ void scan_top_kernel(int* __restrict__ bsum, int nb) {
  __shared__ int tmp[256];
  if ((int)threadIdx.x < nb) tmp[threadIdx.x] = bsum[threadIdx.x];
  __syncthreads();
  if (threadIdx.x == 0) {
    int run = 0;
    for (int i = 0; i < nb; ++i) { const int c = tmp[i]; tmp[i] = run; run += c; }
  }
  __syncthreads();
  if ((int)threadIdx.x < nb) bsum[threadIdx.x] = tmp[threadIdx.x];
}

__global__ __launch_bounds__(SCAN_BLK) void scan_apply_kernel(
    int* __restrict__ ptr, int n, const int* __restrict__ bsum) {
  __shared__ int wsum[SCAN_BLK / 64];
  const int lane = threadIdx.x & 63, wid = threadIdx.x >> 6;
  const int base = blockIdx.x * SCAN_CHUNK + threadIdx.x * 8;
  int v[8];
  int tot = 0;
#pragma unroll
  for (int k = 0; k < 8; ++k) {
    const int idx = base + k;
    v[k] = (idx < n) ? ptr[idx] : 0;
    tot += v[k];
  }
  int sc = tot;  // inclusive wave scan
  for (int d = 1; d < 64; d <<= 1) {
    const int o = __shfl_up(sc, d);
    if (lane >= d) sc += o;
  }
  if (lane == 63) wsum[wid] = sc;
  __syncthreads();
  int woff = 0;
  for (int w = 0; w < wid; ++w) woff += wsum[w];
  int run = bsum[blockIdx.x] + woff + sc - tot;  // exclusive offset
#pragma unroll
  for (int k = 0; k < 8; ++k) {
    const int idx = base + k;
    if (idx < n) ptr[idx] = run;
    run += v[k];
  }
}

// ---------------------------------------------------------------------------
// Cursor scatter, 4 nnz per thread for atomic ILP.
// U-side: writes csrU[pu] = {col, val_bits} (direct data, no indirection).
// P-side: writes permP[pp] = nnz index.
// ---------------------------------------------------------------------------
__global__ __launch_bounds__(256) void scatter_kernel(
    const int* __restrict__ rows, const int* __restrict__ cols,
    const float* __restrict__ up_vals,
    int* __restrict__ ptrU, int* __restrict__ ptrP,
    int2* __restrict__ csrU, int* __restrict__ permP, int nnz) {
  const int t = blockIdx.x * blockDim.x + threadIdx.x;
  const int i0 = t * 4;
  if (i0 + 3 < nnz) {
    const int4 r = ((const int4*)rows)[t];
    const int4 c = ((const int4*)cols)[t];
    const float4 v = ((const float4*)up_vals)[t];
    const int pu0 = atomicAdd(&ptrU[r.x], 1);
    const int pu1 = atomicAdd(&ptrU[r.y], 1);
    const int pu2 = atomicAdd(&ptrU[r.z], 1);
    const int pu3 = atomicAdd(&ptrU[r.w], 1);
    const int pp0 = atomicAdd(&ptrP[c.x], 1);
    const int pp1 = atomicAdd(&ptrP[c.y], 1);
    const int pp2 = atomicAdd(&ptrP[c.z], 1);
    const int pp3 = atomicAdd(&ptrP[c.w], 1);
    csrU[pu0] = make_int2(c.x, __float_as_int(v.x));
    csrU[pu1] = make_int2(c.y, __float_as_int(v.y));
    csrU[pu2] = make_int2(c.z, __float_as_int(v.z));
    csrU[pu3] = make_int2(c.w, __float_as_int(v.w));
    permP[pp0] = i0;
    permP[pp1] = i0 + 1;
    permP[pp2] = i0 + 2;
    permP[pp3] = i0 + 3;
  } else {
    for (int i = i0; i < nnz; ++i) {
      const int rr = rows[i], cc = cols[i];
      const int pu = atomicAdd(&ptrU[rr], 1);
      csrU[pu] = make_int2(cc, __float_as_int(up_vals[i]));
      const int pp = atomicAdd(&ptrP[cc], 1);
      permP[pp] = i;
    }
  }
}

// ---------------------------------------------------------------------------
// Per-user gather, float4-vectorized, 4 nnz per step, coalesced csrU batch
// loads. lane = (sub = lane>>4, d4 = lane&15). No LDS -> full occupancy.
// ---------------------------------------------------------------------------
__global__ __launch_bounds__(256) void user_gather_kernel(
    const int* __restrict__ ptrU, const int2* __restrict__ csrU,
    const float* __restrict__ geo, const float* __restrict__ seq,
    const float* __restrict__ colp,
    float* __restrict__ gw, float* __restrict__ sw, float* __restrict__ pw,
    int U) {
  const int lane = threadIdx.x & 63;
  const int sub = lane >> 4, d4 = lane & 15;
  const int wv = blockIdx.x * 4 + (threadIdx.x >> 6);
  const int nW = gridDim.x * 4;
  for (int u = wv; u < U; u += nW) {
    const int start = (u == 0) ? 0 : ptrU[u - 1];
    const int end = ptrU[u];
    float4 g4 = {0, 0, 0, 0}, s4 = {0, 0, 0, 0}, p4 = {0, 0, 0, 0};
    for (int k0 = start; k0 < end; k0 += 64) {
      int c_v = 0;
      float v_v = 0.f;
      const int kk = k0 + lane;
      if (kk < end) {
        const int2 e = csrU[kk];
        c_v = e.x;
        v_v = __int_as_float(e.y);
      }
      const int steps = (min(64, end - k0) + 3) >> 2;
      for (int t = 0; t < steps; ++t) {
        const int src = t * 4 + sub;
        const int cc = __shfl(c_v, src);
        const float vv = __shfl(v_v, src);
        const float4* gp = (const float4*)(geo + (size_t)cc * EDIM);
        const float4* sp = (const float4*)(seq + (size_t)cc * EDIM);
        const float4* pp = (const float4*)(colp + (size_t)cc * EDIM);
        const float4 a = gp[d4], bb = sp[d4], c = pp[d4];
        g4.x += vv * a.x;  g4.y += vv * a.y;  g4.z += vv * a.z;  g4.w += vv * a.w;
        s4.x += vv * bb.x; s4.y += vv * bb.y; s4.z += vv * bb.z; s4.w += vv * bb.w;
        p4.x += vv * c.x;  p4.y += vv * c.y;  p4.z += vv * c.z;  p4.w += vv * c.w;
      }
    }
#pragma unroll
    for (int m = 16; m <= 32; m <<= 1) {
      g4.x += __shfl_xor(g4.x, m); g4.y += __shfl_xor(g4.y, m);
      g4.z += __shfl_xor(g4.z, m); g4.w += __shfl_xor(g4.w, m);
      s4.x += __shfl_xor(s4.x, m); s4.y += __shfl_xor(s4.y, m);
      s4.z += __shfl_xor(s4.z, m); s4.w += __shfl_xor(s4.w, m);
      p4.x += __shfl_xor(p4.x, m); p4.y += __shfl_xor(p4.y, m);
      p4.z += __shfl_xor(p4.z, m); p4.w += __shfl_xor(p4.w, m);
    }
    if (sub == 0) {
      ((float4*)(gw + (size_t)u * EDIM))[d4] = g4;
      ((float4*)(sw + (size_t)u * EDIM))[d4] = s4;
      ((float4*)(pw + (size_t)u * EDIM))[d4] = p4;
    }
  }
}

// ---------------------------------------------------------------------------
// Fusion: msg @ W^T + bias + gated merge. W^T in LDS padded to stride 65.
// ---------------------------------------------------------------------------
#define FBLK 1024
__global__ __launch_bounds__(FBLK) void fusion_kernel(
    const float* __restrict__ ga, const float* __restrict__ sa,
    const float* __restrict__ pa, const float* __restrict__ uemb,
    const float* __restrict__ W, const float* __restrict__ b,
    float* __restrict__ hg, int U) {
  extern __shared__ float wt[];  // [448][65]
  for (int idx = threadIdx.x; idx < 448 * 64; idx += FBLK) {
    const int e = idx / 448;
    const int f = idx - e * 448;
    wt[f * 65 + e] = W[idx];
  }
  __syncthreads();
  const int lane = threadIdx.x & 63;
  const int wv = blockIdx.x * (FBLK / 64) + (threadIdx.x >> 6);
  const int nW = gridDim.x * (FBLK / 64);
  const float bias = b[lane];

  for (int u0 = wv * 4; u0 < U; u0 += nW * 4) {
    const int cnt = min(4, U - u0);
    float g[4], s[4], p[4], acc[4];
#pragma unroll
    for (int i = 0; i < 4; ++i) {
      const int u = u0 + (i < cnt ? i : 0);
      const size_t off = (size_t)u * EDIM + lane;
      g[i] = ga[off]; s[i] = sa[off]; p[i] = pa[off];
      acc[i] = 0.f;
    }
    for (int j = 0; j < 64; ++j) {
      const int basej = j * 65 + lane;
      const float w0 = wt[basej];
      const float w1 = wt[basej + 64 * 65];
      const float w2 = wt[basej + 128 * 65];
      const float w3 = wt[basej + 192 * 65];
      const float w4 = wt[basej + 256 * 65];
      const float w5 = wt[basej + 320 * 65];
      const float w6 = wt[basej + 384 * 65];
#pragma unroll
      for (int i = 0; i < 4; ++i) {
        const float gj = __shfl(g[i], j);
        const float sj = __shfl(s[i], j);
        const float pj = __shfl(p[i], j);
        const float gs = gj * sj, gp = gj * pj, sp = sj * pj;
        acc[i] += w0 * gj + w1 * sj + w2 * pj + w3 * gs + w4 * gp + w5 * sp +
                  w6 * gs * pj;
      }
    }
#pragma unroll
    for (int i = 0; i < 4; ++i) {
      if (i < cnt) {
        const float me = acc[i] + bias;
        const size_t off = (size_t)(u0 + i) * EDIM + lane;
        const float ue = uemb[off];
        hg[off] = me + ue + me * ue;
      }
    }
  }
}

// ---------------------------------------------------------------------------
// Per-POI gather (transpose side), float4-vectorized, fused with mean:
// out = init + (L/2)*acc.
// ---------------------------------------------------------------------------
__global__ __launch_bounds__(256) void poi_gather_kernel(
    const int* __restrict__ ptrP, const int* __restrict__ permP,
    const int* __restrict__ rows, const float* __restrict__ pu_vals,
    const float* __restrict__ hg, const float* __restrict__ init,
    const int* __restrict__ num_layers, float* __restrict__ out, int P) {
  const float scale = 0.5f * (float)num_layers[0];
  const int lane = threadIdx.x & 63;
  const int sub = lane >> 4, d4 = lane & 15;
  const int wv = blockIdx.x * 4 + (threadIdx.x >> 6);
  const int nW = gridDim.x * 4;
  for (int c = wv; c < P; c += nW) {
    const int start = (c == 0) ? 0 : ptrP[c - 1];
    const int end = ptrP[c];
    float4 a4 = {0, 0, 0, 0};
    for (int k0 = start; k0 < end; k0 += 64) {
      int r_v = 0;
      float v_v = 0.f;
      const int kk = k0 + lane;
      if (kk < end) {
        const int id = permP[kk];
        r_v = rows[id];
        v_v = pu_vals[id];
      }
      const int steps = (min(64, end - k0) + 3) >> 2;
      for (int t = 0; t < steps; ++t) {
        const int src = t * 4 + sub;
        const int rr = __shfl(r_v, src);
        const float vv = __shfl(v_v, src);
        const float4 h = ((const float4*)(hg + (size_t)rr * EDIM))[d4];
        a4.x += vv * h.x; a4.y += vv * h.y; a4.z += vv * h.z; a4.w += vv * h.w;
      }
    }
#pragma unroll
    for (int m = 16; m <= 32; m <<= 1) {
      a4.x += __shfl_xor(a4.x, m); a4.y += __shfl_xor(a4.y, m);
      a4.z += __shfl_xor(a4.z, m); a4.w += __shfl_xor(a4.w, m);
    }
    if (sub == 0) {
      const float4 iv = ((const float4*)(init + (size_t)c * EDIM))[d4];
      float4 o;
      o.x = iv.x + scale * a4.x;
      o.y = iv.y + scale * a4.y;
      o.z = iv.z + scale * a4.z;
      o.w = iv.w + scale * a4.w;
      ((float4*)(out + (size_t)c * EDIM))[d4] = o;
    }
  }
}

extern "C" void kernel_launch(void* const* d_in, const int* in_sizes, int n_in,
                              void* d_out, int out_size, void* d_ws,
                              size_t ws_size, hipStream_t stream) {
  const float* init = (const float*)d_in[0];
  const float* colp = (const float*)d_in[1];
  const float* geo = (const float*)d_in[2];
  const float* seq = (const float*)d_in[3];
  const float* uemb = (const float*)d_in[4];
  const int* up_rows = (const int*)d_in[5];
  const int* up_cols = (const int*)d_in[6];
  const float* up_vals = (const float*)d_in[7];
  const float* pu_vals = (const float*)d_in[8];
  const float* W = (const float*)d_in[9];
  const float* b = (const float*)d_in[10];
  const int* num_layers = (const int*)d_in[11];

  const int U = in_sizes[4] / EDIM;
  const int P = in_sizes[0] / EDIM;
  const int NNZ = in_sizes[5];

  int* ptrU = (int*)d_ws;            // U
  int* ptrP = ptrU + U;              // P
  int2* csrU = (int2*)(ptrP + P);    // NNZ int2 (col, val_bits)
  int* permP = (int*)(csrU + NNZ);   // NNZ
  int* bsumU = permP + NNZ;          // 256
  int* bsumP = bsumU + 256;          // 256
  float* ga = (float*)(bsumP + 256); // U*64 (hg aliases this)
  float* sa = ga + (size_t)U * EDIM;
  float* pa = sa + (size_t)U * EDIM;
  float* hg = ga;  // in-place overwrite in fusion_kernel
  float* out = (float*)d_out;

  const int nbU = (U + SCAN_CHUNK - 1) / SCAN_CHUNK;
  const int nbP = (P + SCAN_CHUNK - 1) / SCAN_CHUNK;
  const int nb4 = (NNZ / 4 + 255) / 256 + 1;  // threads of 4 nnz each (+tail)

  hipMemsetAsync(ptrU, 0, (size_t)(U + P) * sizeof(int), stream);

  hist_kernel<<<nb4, 256, 0, stream>>>(up_rows, up_cols, ptrU, ptrP, NNZ);

  scan_reduce_kernel<<<nbU, SCAN_BLK, 0, stream>>>(ptrU, U, bsumU);
  scan_reduce_kernel<<<nbP, SCAN_BLK, 0, stream>>>(ptrP, P, bsumP);
  scan_top_kernel<<<1, 256, 0, stream>>>(bsumU, nbU);
  scan_top_kernel<<<1, 256, 0, stream>>>(bsumP, nbP);
  scan_apply_kernel<<<nbU, SCAN_BLK, 0, stream>>>(ptrU, U, bsumU);
  scan_apply_kernel<<<nbP, SCAN_BLK, 0, stream>>>(ptrP, P, bsumP);

  scatter_kernel<<<nb4, 256, 0, stream>>>(up_rows, up_cols, up_vals, ptrU,
                                          ptrP, csrU, permP, NNZ);

  user_gather_kernel<<<2048, 256, 0, stream>>>(ptrU, csrU, geo, seq, colp,
                                               ga, sa, pa, U);

  fusion_kernel<<<256, FBLK, 448 * 65 * sizeof(float), stream>>>(
      ga, sa, pa, uemb, W, b, hg, U);

  poi_gather_kernel<<<2048, 256, 0, stream>>>(ptrP, permP, up_rows, pu_vals,
                                              hg, init, num_layers, out, P);
}

// Round 5
// 945.905 us; speedup vs baseline: 1.3652x; 1.2747x over previous
//
#include <hip/hip_runtime.h>

#define EDIM 64
#define SCAN_BLK 256
#define SCAN_CHUNK 2048  // 8 elements per thread

// ---------------------------------------------------------------------------
// Histogram with rank capture: rank[i] = old count. The returning atomic here
// replaces a second full random-atomic pass in scatter.
// ---------------------------------------------------------------------------
__global__ __launch_bounds__(256) void hist_rank_kernel(
    const int* __restrict__ rows, const int* __restrict__ cols,
    int* __restrict__ cntU, int* __restrict__ cntP,
    int* __restrict__ rankU, int* __restrict__ rankP, int nnz) {
  const int t = blockIdx.x * blockDim.x + threadIdx.x;
  const int i0 = t * 4;
  if (i0 + 3 < nnz) {
    const int4 r = ((const int4*)rows)[t];
    const int4 c = ((const int4*)cols)[t];
    int4 ru, rp;
    ru.x = atomicAdd(&cntU[r.x], 1);
    ru.y = atomicAdd(&cntU[r.y], 1);
    ru.z = atomicAdd(&cntU[r.z], 1);
    ru.w = atomicAdd(&cntU[r.w], 1);
    rp.x = atomicAdd(&cntP[c.x], 1);
    rp.y = atomicAdd(&cntP[c.y], 1);
    rp.z = atomicAdd(&cntP[c.z], 1);
    rp.w = atomicAdd(&cntP[c.w], 1);
    ((int4*)rankU)[t] = ru;
    ((int4*)rankP)[t] = rp;
  } else {
    for (int i = i0; i < nnz; ++i) {
      rankU[i] = atomicAdd(&cntU[rows[i]], 1);
      rankP[i] = atomicAdd(&cntP[cols[i]], 1);
    }
  }
}

// ---------------------------------------------------------------------------
// Hierarchical exclusive scan (unchanged).
// ---------------------------------------------------------------------------
__global__ __launch_bounds__(SCAN_BLK) void scan_reduce_kernel(
    const int* __restrict__ cnt, int n, int* __restrict__ bsum) {
  __shared__ int wsh[SCAN_BLK / 64];
  const int lane = threadIdx.x & 63, wid = threadIdx.x >> 6;
  const int base = blockIdx.x * SCAN_CHUNK + threadIdx.x * 8;
  int s = 0;
#pragma unroll
  for (int k = 0; k < 8; ++k) {
    const int idx = base + k;
    if (idx < n) s += cnt[idx];
  }
  for (int d = 32; d; d >>= 1) s += __shfl_down(s, d);
  if (lane == 0) wsh[wid] = s;
  __syncthreads();
  if (threadIdx.x == 0) {
    int t = 0;
    for (int w = 0; w < SCAN_BLK / 64; ++w) t += wsh[w];
    bsum[blockIdx.x] = t;
  }
}

__global__ void scan_top_kernel(int* __restrict__ bsum, int nb) {
  __shared__ int tmp[256];
  if ((int)threadIdx.x < nb) tmp[threadIdx.x] = bsum[threadIdx.x];
  __syncthreads();
  if (threadIdx.x == 0) {
    int run = 0;
    for (int i = 0; i < nb; ++i) { const int c = tmp[i]; tmp[i] = run; run += c; }
  }
  __syncthreads();
  if ((int)threadIdx.x < nb) bsum[threadIdx.x] = tmp[threadIdx.x];
}

__global__ __launch_bounds__(SCAN_BLK) void scan_apply_kernel(
    int* __restrict__ ptr, int n, const int* __restrict__ bsum) {
  __shared__ int wsum[SCAN_BLK / 64];
  const int lane = threadIdx.x & 63, wid = threadIdx.x >> 6;
  const int base = blockIdx.x * SCAN_CHUNK + threadIdx.x * 8;
  int v[8];
  int tot = 0;
#pragma unroll
  for (int k = 0; k < 8; ++k) {
    const int idx = base + k;
    v[k] = (idx < n) ? ptr[idx] : 0;
    tot += v[k];
  }
  int sc = tot;  // inclusive wave scan
  for (int d = 1; d < 64; d <<= 1) {
    const int o = __shfl_up(sc, d);
    if (lane >= d) sc += o;
  }
  if (lane == 63) wsum[wid] = sc;
  __syncthreads();
  int woff = 0;
  for (int w = 0; w < wid; ++w) woff += wsum[w];
  int run = bsum[blockIdx.x] + woff + sc - tot;  // exclusive offset
#pragma unroll
  for (int k = 0; k < 8; ++k) {
    const int idx = base + k;
    if (idx < n) ptr[idx] = run;
    run += v[k];
  }
}

// ---------------------------------------------------------------------------
// Atomic-free scatter: pos = ptr[key] + rank. ptr gathers are L2-resident
// (1.2 MB). Only the final stores are random.
// U-side: csrU[pos] = {col, val_bits}. P-side: permP[pos] = nnz index.
// ---------------------------------------------------------------------------
__global__ __launch_bounds__(256) void scatter_kernel(
    const int* __restrict__ rows, const int* __restrict__ cols,
    const float* __restrict__ up_vals,
    const int* __restrict__ ptrU, const int* __restrict__ ptrP,
    const int* __restrict__ rankU, const int* __restrict__ rankP,
    int2* __restrict__ csrU, int* __restrict__ permP, int nnz) {
  const int t = blockIdx.x * blockDim.x + threadIdx.x;
  const int i0 = t * 4;
  if (i0 + 3 < nnz) {
    const int4 r = ((const int4*)rows)[t];
    const int4 c = ((const int4*)cols)[t];
    const float4 v = ((const float4*)up_vals)[t];
    const int4 ru = ((const int4*)rankU)[t];
    const int4 rp = ((const int4*)rankP)[t];
    const int pu0 = ptrU[r.x] + ru.x;
    const int pu1 = ptrU[r.y] + ru.y;
    const int pu2 = ptrU[r.z] + ru.z;
    const int pu3 = ptrU[r.w] + ru.w;
    const int pp0 = ptrP[c.x] + rp.x;
    const int pp1 = ptrP[c.y] + rp.y;
    const int pp2 = ptrP[c.z] + rp.z;
    const int pp3 = ptrP[c.w] + rp.w;
    csrU[pu0] = make_int2(c.x, __float_as_int(v.x));
    csrU[pu1] = make_int2(c.y, __float_as_int(v.y));
    csrU[pu2] = make_int2(c.z, __float_as_int(v.z));
    csrU[pu3] = make_int2(c.w, __float_as_int(v.w));
    permP[pp0] = i0;
    permP[pp1] = i0 + 1;
    permP[pp2] = i0 + 2;
    permP[pp3] = i0 + 3;
  } else {
    for (int i = i0; i < nnz; ++i) {
      const int rr = rows[i], cc = cols[i];
      csrU[ptrU[rr] + rankU[i]] = make_int2(cc, __float_as_int(up_vals[i]));
      permP[ptrP[cc] + rankP[i]] = i;
    }
  }
}

// ---------------------------------------------------------------------------
// Per-user gather, float4-vectorized, 4 nnz per step, coalesced csrU batch
// loads. ptrU holds exclusive offsets: start=ptrU[u], end=ptrU[u+1] (or nnz).
// ---------------------------------------------------------------------------
__global__ __launch_bounds__(256) void user_gather_kernel(
    const int* __restrict__ ptrU, const int2* __restrict__ csrU,
    const float* __restrict__ geo, const float* __restrict__ seq,
    const float* __restrict__ colp,
    float* __restrict__ gw, float* __restrict__ sw, float* __restrict__ pw,
    int U, int nnz) {
  const int lane = threadIdx.x & 63;
  const int sub = lane >> 4, d4 = lane & 15;
  const int wv = blockIdx.x * 4 + (threadIdx.x >> 6);
  const int nW = gridDim.x * 4;
  for (int u = wv; u < U; u += nW) {
    const int start = ptrU[u];
    const int end = (u + 1 < U) ? ptrU[u + 1] : nnz;
    float4 g4 = {0, 0, 0, 0}, s4 = {0, 0, 0, 0}, p4 = {0, 0, 0, 0};
    for (int k0 = start; k0 < end; k0 += 64) {
      int c_v = 0;
      float v_v = 0.f;
      const int kk = k0 + lane;
      if (kk < end) {
        const int2 e = csrU[kk];
        c_v = e.x;
        v_v = __int_as_float(e.y);
      }
      const int steps = (min(64, end - k0) + 3) >> 2;
      for (int t = 0; t < steps; ++t) {
        const int src = t * 4 + sub;
        const int cc = __shfl(c_v, src);
        const float vv = __shfl(v_v, src);
        const float4* gp = (const float4*)(geo + (size_t)cc * EDIM);
        const float4* sp = (const float4*)(seq + (size_t)cc * EDIM);
        const float4* pp = (const float4*)(colp + (size_t)cc * EDIM);
        const float4 a = gp[d4], bb = sp[d4], c = pp[d4];
        g4.x += vv * a.x;  g4.y += vv * a.y;  g4.z += vv * a.z;  g4.w += vv * a.w;
        s4.x += vv * bb.x; s4.y += vv * bb.y; s4.z += vv * bb.z; s4.w += vv * bb.w;
        p4.x += vv * c.x;  p4.y += vv * c.y;  p4.z += vv * c.z;  p4.w += vv * c.w;
      }
    }
#pragma unroll
    for (int m = 16; m <= 32; m <<= 1) {
      g4.x += __shfl_xor(g4.x, m); g4.y += __shfl_xor(g4.y, m);
      g4.z += __shfl_xor(g4.z, m); g4.w += __shfl_xor(g4.w, m);
      s4.x += __shfl_xor(s4.x, m); s4.y += __shfl_xor(s4.y, m);
      s4.z += __shfl_xor(s4.z, m); s4.w += __shfl_xor(s4.w, m);
      p4.x += __shfl_xor(p4.x, m); p4.y += __shfl_xor(p4.y, m);
      p4.z += __shfl_xor(p4.z, m); p4.w += __shfl_xor(p4.w, m);
    }
    if (sub == 0) {
      ((float4*)(gw + (size_t)u * EDIM))[d4] = g4;
      ((float4*)(sw + (size_t)u * EDIM))[d4] = s4;
      ((float4*)(pw + (size_t)u * EDIM))[d4] = p4;
    }
  }
}

// ---------------------------------------------------------------------------
// Fusion: msg @ W^T + bias + gated merge. W^T in LDS padded to stride 65.
// ---------------------------------------------------------------------------
#define FBLK 1024
__global__ __launch_bounds__(FBLK) void fusion_kernel(
    const float* __restrict__ ga, const float* __restrict__ sa,
    const float* __restrict__ pa, const float* __restrict__ uemb,
    const float* __restrict__ W, const float* __restrict__ b,
    float* __restrict__ hg, int U) {
  extern __shared__ float wt[];  // [448][65]
  for (int idx = threadIdx.x; idx < 448 * 64; idx += FBLK) {
    const int e = idx / 448;
    const int f = idx - e * 448;
    wt[f * 65 + e] = W[idx];
  }
  __syncthreads();
  const int lane = threadIdx.x & 63;
  const int wv = blockIdx.x * (FBLK / 64) + (threadIdx.x >> 6);
  const int nW = gridDim.x * (FBLK / 64);
  const float bias = b[lane];

  for (int u0 = wv * 4; u0 < U; u0 += nW * 4) {
    const int cnt = min(4, U - u0);
    float g[4], s[4], p[4], acc[4];
#pragma unroll
    for (int i = 0; i < 4; ++i) {
      const int u = u0 + (i < cnt ? i : 0);
      const size_t off = (size_t)u * EDIM + lane;
      g[i] = ga[off]; s[i] = sa[off]; p[i] = pa[off];
      acc[i] = 0.f;
    }
    for (int j = 0; j < 64; ++j) {
      const int basej = j * 65 + lane;
      const float w0 = wt[basej];
      const float w1 = wt[basej + 64 * 65];
      const float w2 = wt[basej + 128 * 65];
      const float w3 = wt[basej + 192 * 65];
      const float w4 = wt[basej + 256 * 65];
      const float w5 = wt[basej + 320 * 65];
      const float w6 = wt[basej + 384 * 65];
#pragma unroll
      for (int i = 0; i < 4; ++i) {
        const float gj = __shfl(g[i], j);
        const float sj = __shfl(s[i], j);
        const float pj = __shfl(p[i], j);
        const float gs = gj * sj, gp = gj * pj, sp = sj * pj;
        acc[i] += w0 * gj + w1 * sj + w2 * pj + w3 * gs + w4 * gp + w5 * sp +
                  w6 * gs * pj;
      }
    }
#pragma unroll
    for (int i = 0; i < 4; ++i) {
      if (i < cnt) {
        const float me = acc[i] + bias;
        const size_t off = (size_t)(u0 + i) * EDIM + lane;
        const float ue = uemb[off];
        hg[off] = me + ue + me * ue;
      }
    }
  }
}

// ---------------------------------------------------------------------------
// Per-POI gather (transpose side), float4-vectorized, fused with mean:
// out = init + (L/2)*acc. ptrP holds exclusive offsets.
// ---------------------------------------------------------------------------
__global__ __launch_bounds__(256) void poi_gather_kernel(
    const int* __restrict__ ptrP, const int* __restrict__ permP,
    const int* __restrict__ rows, const float* __restrict__ pu_vals,
    const float* __restrict__ hg, const float* __restrict__ init,
    const int* __restrict__ num_layers, float* __restrict__ out, int P,
    int nnz) {
  const float scale = 0.5f * (float)num_layers[0];
  const int lane = threadIdx.x & 63;
  const int sub = lane >> 4, d4 = lane & 15;
  const int wv = blockIdx.x * 4 + (threadIdx.x >> 6);
  const int nW = gridDim.x * 4;
  for (int c = wv; c < P; c += nW) {
    const int start = ptrP[c];
    const int end = (c + 1 < P) ? ptrP[c + 1] : nnz;
    float4 a4 = {0, 0, 0, 0};
    for (int k0 = start; k0 < end; k0 += 64) {
      int r_v = 0;
      float v_v = 0.f;
      const int kk = k0 + lane;
      if (kk < end) {
        const int id = permP[kk];
        r_v = rows[id];
        v_v = pu_vals[id];
      }
      const int steps = (min(64, end - k0) + 3) >> 2;
      for (int t = 0; t < steps; ++t) {
        const int src = t * 4 + sub;
        const int rr = __shfl(r_v, src);
        const float vv = __shfl(v_v, src);
        const float4 h = ((const float4*)(hg + (size_t)rr * EDIM))[d4];
        a4.x += vv * h.x; a4.y += vv * h.y; a4.z += vv * h.z; a4.w += vv * h.w;
      }
    }
#pragma unroll
    for (int m = 16; m <= 32; m <<= 1) {
      a4.x += __shfl_xor(a4.x, m); a4.y += __shfl_xor(a4.y, m);
      a4.z += __shfl_xor(a4.z, m); a4.w += __shfl_xor(a4.w, m);
    }
    if (sub == 0) {
      const float4 iv = ((const float4*)(init + (size_t)c * EDIM))[d4];
      float4 o;
      o.x = iv.x + scale * a4.x;
      o.y = iv.y + scale * a4.y;
      o.z = iv.z + scale * a4.z;
      o.w = iv.w + scale * a4.w;
      ((float4*)(out + (size_t)c * EDIM))[d4] = o;
    }
  }
}

extern "C" void kernel_launch(void* const* d_in, const int* in_sizes, int n_in,
                              void* d_out, int out_size, void* d_ws,
                              size_t ws_size, hipStream_t stream) {
  const float* init = (const float*)d_in[0];
  const float* colp = (const float*)d_in[1];
  const float* geo = (const float*)d_in[2];
  const float* seq = (const float*)d_in[3];
  const float* uemb = (const float*)d_in[4];
  const int* up_rows = (const int*)d_in[5];
  const int* up_cols = (const int*)d_in[6];
  const float* up_vals = (const float*)d_in[7];
  const float* pu_vals = (const float*)d_in[8];
  const float* W = (const float*)d_in[9];
  const float* b = (const float*)d_in[10];
  const int* num_layers = (const int*)d_in[11];

  const int U = in_sizes[4] / EDIM;
  const int P = in_sizes[0] / EDIM;
  const int NNZ = in_sizes[5];

  int* ptrU = (int*)d_ws;            // U (counts -> exclusive offsets)
  int* ptrP = ptrU + U;              // P
  int2* csrU = (int2*)(ptrP + P);    // NNZ int2 (col, val_bits)
  int* permP = (int*)(csrU + NNZ);   // NNZ
  int* bsumU = permP + NNZ;          // 256
  int* bsumP = bsumU + 256;          // 256
  float* ga = (float*)(bsumP + 256); // U*64 (hg aliases this)
  float* sa = ga + (size_t)U * EDIM;
  float* pa = sa + (size_t)U * EDIM;
  float* hg = ga;  // in-place overwrite in fusion_kernel
  // rank arrays alias ga/sa (dead before user_gather writes them)
  int* rankU = (int*)ga;             // NNZ
  int* rankP = rankU + NNZ;          // NNZ
  float* out = (float*)d_out;

  const int nbU = (U + SCAN_CHUNK - 1) / SCAN_CHUNK;
  const int nbP = (P + SCAN_CHUNK - 1) / SCAN_CHUNK;
  const int nb4 = (NNZ / 4 + 255) / 256 + 1;  // threads of 4 nnz each (+tail)

  hipMemsetAsync(ptrU, 0, (size_t)(U + P) * sizeof(int), stream);

  hist_rank_kernel<<<nb4, 256, 0, stream>>>(up_rows, up_cols, ptrU, ptrP,
                                            rankU, rankP, NNZ);

  scan_reduce_kernel<<<nbU, SCAN_BLK, 0, stream>>>(ptrU, U, bsumU);
  scan_reduce_kernel<<<nbP, SCAN_BLK, 0, stream>>>(ptrP, P, bsumP);
  scan_top_kernel<<<1, 256, 0, stream>>>(bsumU, nbU);
  scan_top_kernel<<<1, 256, 0, stream>>>(bsumP, nbP);
  scan_apply_kernel<<<nbU, SCAN_BLK, 0, stream>>>(ptrU, U, bsumU);
  scan_apply_kernel<<<nbP, SCAN_BLK, 0, stream>>>(ptrP, P, bsumP);

  scatter_kernel<<<nb4, 256, 0, stream>>>(up_rows, up_cols, up_vals, ptrU,
                                          ptrP, rankU, rankP, csrU, permP,
                                          NNZ);

  user_gather_kernel<<<2048, 256, 0, stream>>>(ptrU, csrU, geo, seq, colp,
                                               ga, sa, pa, U, NNZ);

  fusion_kernel<<<256, FBLK, 448 * 65 * sizeof(float), stream>>>(
      ga, sa, pa, uemb, W, b, hg, U);

  poi_gather_kernel<<<2048, 256, 0, stream>>>(ptrP, permP, up_rows, pu_vals,
                                              hg, init, num_layers, out, P,
                                              NNZ);
}

// Round 6
// 695.807 us; speedup vs baseline: 1.8558x; 1.3594x over previous
//
#include <hip/hip_runtime.h>

#define EDIM 64
#define SCAN_BLK 256
#define SCAN_CHUNK 2048  // 8 elements per thread

typedef __attribute__((ext_vector_type(8))) short short8;
typedef __attribute__((ext_vector_type(4))) float f32x4;

// f32 -> bf16 round-to-nearest-even
__device__ __forceinline__ unsigned short f2bf(float x) {
  unsigned int u = __float_as_uint(x);
  u += 0x7FFFu + ((u >> 16) & 1u);
  return (unsigned short)(u >> 16);
}
__device__ __forceinline__ float bf2f(unsigned short s) {
  return __uint_as_float(((unsigned int)s) << 16);
}

// ---------------------------------------------------------------------------
// Histogram with rank capture: rank[i] = old count.
// ---------------------------------------------------------------------------
__global__ __launch_bounds__(256) void hist_rank_kernel(
    const int* __restrict__ rows, const int* __restrict__ cols,
    int* __restrict__ cntU, int* __restrict__ cntP,
    int* __restrict__ rankU, int* __restrict__ rankP, int nnz) {
  const int t = blockIdx.x * blockDim.x + threadIdx.x;
  const int i0 = t * 4;
  if (i0 + 3 < nnz) {
    const int4 r = ((const int4*)rows)[t];
    const int4 c = ((const int4*)cols)[t];
    int4 ru, rp;
    ru.x = atomicAdd(&cntU[r.x], 1);
    ru.y = atomicAdd(&cntU[r.y], 1);
    ru.z = atomicAdd(&cntU[r.z], 1);
    ru.w = atomicAdd(&cntU[r.w], 1);
    rp.x = atomicAdd(&cntP[c.x], 1);
    rp.y = atomicAdd(&cntP[c.y], 1);
    rp.z = atomicAdd(&cntP[c.z], 1);
    rp.w = atomicAdd(&cntP[c.w], 1);
    ((int4*)rankU)[t] = ru;
    ((int4*)rankP)[t] = rp;
  } else {
    for (int i = i0; i < nnz; ++i) {
      rankU[i] = atomicAdd(&cntU[rows[i]], 1);
      rankP[i] = atomicAdd(&cntP[cols[i]], 1);
    }
  }
}

// ---------------------------------------------------------------------------
// Hierarchical exclusive scan (unchanged).
// ---------------------------------------------------------------------------
__global__ __launch_bounds__(SCAN_BLK) void scan_reduce_kernel(
    const int* __restrict__ cnt, int n, int* __restrict__ bsum) {
  __shared__ int wsh[SCAN_BLK / 64];
  const int lane = threadIdx.x & 63, wid = threadIdx.x >> 6;
  const int base = blockIdx.x * SCAN_CHUNK + threadIdx.x * 8;
  int s = 0;
#pragma unroll
  for (int k = 0; k < 8; ++k) {
    const int idx = base + k;
    if (idx < n) s += cnt[idx];
  }
  for (int d = 32; d; d >>= 1) s += __shfl_down(s, d);
  if (lane == 0) wsh[wid] = s;
  __syncthreads();
  if (threadIdx.x == 0) {
    int t = 0;
    for (int w = 0; w < SCAN_BLK / 64; ++w) t += wsh[w];
    bsum[blockIdx.x] = t;
  }
}

__global__ void scan_top_kernel(int* __restrict__ bsum, int nb) {
  __shared__ int tmp[256];
  if ((int)threadIdx.x < nb) tmp[threadIdx.x] = bsum[threadIdx.x];
  __syncthreads();
  if (threadIdx.x == 0) {
    int run = 0;
    for (int i = 0; i < nb; ++i) { const int c = tmp[i]; tmp[i] = run; run += c; }
  }
  __syncthreads();
  if ((int)threadIdx.x < nb) bsum[threadIdx.x] = tmp[threadIdx.x];
}

__global__ __launch_bounds__(SCAN_BLK) void scan_apply_kernel(
    int* __restrict__ ptr, int n, const int* __restrict__ bsum) {
  __shared__ int wsum[SCAN_BLK / 64];
  const int lane = threadIdx.x & 63, wid = threadIdx.x >> 6;
  const int base = blockIdx.x * SCAN_CHUNK + threadIdx.x * 8;
  int v[8];
  int tot = 0;
#pragma unroll
  for (int k = 0; k < 8; ++k) {
    const int idx = base + k;
    v[k] = (idx < n) ? ptr[idx] : 0;
    tot += v[k];
  }
  int sc = tot;  // inclusive wave scan
  for (int d = 1; d < 64; d <<= 1) {
    const int o = __shfl_up(sc, d);
    if (lane >= d) sc += o;
  }
  if (lane == 63) wsum[wid] = sc;
  __syncthreads();
  int woff = 0;
  for (int w = 0; w < wid; ++w) woff += wsum[w];
  int run = bsum[blockIdx.x] + woff + sc - tot;  // exclusive offset
#pragma unroll
  for (int k = 0; k < 8; ++k) {
    const int idx = base + k;
    if (idx < n) ptr[idx] = run;
    run += v[k];
  }
}

// ---------------------------------------------------------------------------
// Atomic-free scatter: pos = ptr[key] + rank.
// ---------------------------------------------------------------------------
__global__ __launch_bounds__(256) void scatter_kernel(
    const int* __restrict__ rows, const int* __restrict__ cols,
    const float* __restrict__ up_vals,
    const int* __restrict__ ptrU, const int* __restrict__ ptrP,
    const int* __restrict__ rankU, const int* __restrict__ rankP,
    int2* __restrict__ csrU, int* __restrict__ permP, int nnz) {
  const int t = blockIdx.x * blockDim.x + threadIdx.x;
  const int i0 = t * 4;
  if (i0 + 3 < nnz) {
    const int4 r = ((const int4*)rows)[t];
    const int4 c = ((const int4*)cols)[t];
    const float4 v = ((const float4*)up_vals)[t];
    const int4 ru = ((const int4*)rankU)[t];
    const int4 rp = ((const int4*)rankP)[t];
    const int pu0 = ptrU[r.x] + ru.x;
    const int pu1 = ptrU[r.y] + ru.y;
    const int pu2 = ptrU[r.z] + ru.z;
    const int pu3 = ptrU[r.w] + ru.w;
    const int pp0 = ptrP[c.x] + rp.x;
    const int pp1 = ptrP[c.y] + rp.y;
    const int pp2 = ptrP[c.z] + rp.z;
    const int pp3 = ptrP[c.w] + rp.w;
    csrU[pu0] = make_int2(c.x, __float_as_int(v.x));
    csrU[pu1] = make_int2(c.y, __float_as_int(v.y));
    csrU[pu2] = make_int2(c.z, __float_as_int(v.z));
    csrU[pu3] = make_int2(c.w, __float_as_int(v.w));
    permP[pp0] = i0;
    permP[pp1] = i0 + 1;
    permP[pp2] = i0 + 2;
    permP[pp3] = i0 + 3;
  } else {
    for (int i = i0; i < nnz; ++i) {
      const int rr = rows[i], cc = cols[i];
      csrU[ptrU[rr] + rankU[i]] = make_int2(cc, __float_as_int(up_vals[i]));
      permP[ptrP[cc] + rankP[i]] = i;
    }
  }
}

// ---------------------------------------------------------------------------
// Per-user gather -> bf16 g/s/p outputs [U][64].
// ---------------------------------------------------------------------------
__global__ __launch_bounds__(256) void user_gather_kernel(
    const int* __restrict__ ptrU, const int2* __restrict__ csrU,
    const float* __restrict__ geo, const float* __restrict__ seq,
    const float* __restrict__ colp,
    unsigned short* __restrict__ gw, unsigned short* __restrict__ sw,
    unsigned short* __restrict__ pw, int U, int nnz) {
  const int lane = threadIdx.x & 63;
  const int sub = lane >> 4, d4 = lane & 15;
  const int wv = blockIdx.x * 4 + (threadIdx.x >> 6);
  const int nW = gridDim.x * 4;
  for (int u = wv; u < U; u += nW) {
    const int start = ptrU[u];
    const int end = (u + 1 < U) ? ptrU[u + 1] : nnz;
    float4 g4 = {0, 0, 0, 0}, s4 = {0, 0, 0, 0}, p4 = {0, 0, 0, 0};
    for (int k0 = start; k0 < end; k0 += 64) {
      int c_v = 0;
      float v_v = 0.f;
      const int kk = k0 + lane;
      if (kk < end) {
        const int2 e = csrU[kk];
        c_v = e.x;
        v_v = __int_as_float(e.y);
      }
      const int steps = (min(64, end - k0) + 3) >> 2;
      for (int t = 0; t < steps; ++t) {
        const int src = t * 4 + sub;
        const int cc = __shfl(c_v, src);
        const float vv = __shfl(v_v, src);
        const float4* gp = (const float4*)(geo + (size_t)cc * EDIM);
        const float4* sp = (const float4*)(seq + (size_t)cc * EDIM);
        const float4* pp = (const float4*)(colp + (size_t)cc * EDIM);
        const float4 a = gp[d4], bb = sp[d4], c = pp[d4];
        g4.x += vv * a.x;  g4.y += vv * a.y;  g4.z += vv * a.z;  g4.w += vv * a.w;
        s4.x += vv * bb.x; s4.y += vv * bb.y; s4.z += vv * bb.z; s4.w += vv * bb.w;
        p4.x += vv * c.x;  p4.y += vv * c.y;  p4.z += vv * c.z;  p4.w += vv * c.w;
      }
    }
#pragma unroll
    for (int m = 16; m <= 32; m <<= 1) {
      g4.x += __shfl_xor(g4.x, m); g4.y += __shfl_xor(g4.y, m);
      g4.z += __shfl_xor(g4.z, m); g4.w += __shfl_xor(g4.w, m);
      s4.x += __shfl_xor(s4.x, m); s4.y += __shfl_xor(s4.y, m);
      s4.z += __shfl_xor(s4.z, m); s4.w += __shfl_xor(s4.w, m);
      p4.x += __shfl_xor(p4.x, m); p4.y += __shfl_xor(p4.y, m);
      p4.z += __shfl_xor(p4.z, m); p4.w += __shfl_xor(p4.w, m);
    }
    if (sub == 0) {
      uint2 gp2, sp2, pp2;
      gp2.x = (unsigned int)f2bf(g4.x) | ((unsigned int)f2bf(g4.y) << 16);
      gp2.y = (unsigned int)f2bf(g4.z) | ((unsigned int)f2bf(g4.w) << 16);
      sp2.x = (unsigned int)f2bf(s4.x) | ((unsigned int)f2bf(s4.y) << 16);
      sp2.y = (unsigned int)f2bf(s4.z) | ((unsigned int)f2bf(s4.w) << 16);
      pp2.x = (unsigned int)f2bf(p4.x) | ((unsigned int)f2bf(p4.y) << 16);
      pp2.y = (unsigned int)f2bf(p4.z) | ((unsigned int)f2bf(p4.w) << 16);
      ((uint2*)(gw + (size_t)u * EDIM))[d4] = gp2;
      ((uint2*)(sw + (size_t)u * EDIM))[d4] = sp2;
      ((uint2*)(pw + (size_t)u * EDIM))[d4] = pp2;
    }
  }
}

// ---------------------------------------------------------------------------
// Fusion as bf16 MFMA GEMM: msg[U,448] @ W^T[448,64] + bias + gated merge.
// W^T staged in LDS pre-packed in fragment order:
//   frag fe = blk*512 + h*256 + n*64 + lane, 8 bf16 each (16B), 57.3 KB.
//   entry (fe, j): f = blk*64 + h*32 + (lane>>4)*8 + j, e = n*16 + (lane&15).
// Per 16-user tile: build 7 A-frags per K-half from g/s/p rows (products in
// f32, RNE to bf16), 56 mfma_f32_16x16x32_bf16, epilogue merges uemb.
// C/D layout: col = lane&15 (=e sub), row = (lane>>4)*4 + reg (=user sub).
// ---------------------------------------------------------------------------
#define FM_BLK 256
__global__ __launch_bounds__(FM_BLK) void fusion_mfma_kernel(
    const unsigned short* __restrict__ gbf, const unsigned short* __restrict__ sbf,
    const unsigned short* __restrict__ pbf, const float* __restrict__ uemb,
    const float* __restrict__ W, const float* __restrict__ b,
    float* __restrict__ hg, int U) {
  __shared__ unsigned short wlds[7 * 2 * 4 * 64 * 8];  // 57344 B
  for (int fe = threadIdx.x; fe < 7 * 2 * 4 * 64; fe += FM_BLK) {
    const int ln = fe & 63;
    const int n = (fe >> 6) & 3;
    const int h = (fe >> 8) & 1;
    const int blk = fe >> 9;
    const int e = n * 16 + (ln & 15);
    const int f0 = blk * 64 + h * 32 + (ln >> 4) * 8;
    const float* wsrc = W + (size_t)e * 448 + f0;
    uint4 w4;
    w4.x = (unsigned int)f2bf(wsrc[0]) | ((unsigned int)f2bf(wsrc[1]) << 16);
    w4.y = (unsigned int)f2bf(wsrc[2]) | ((unsigned int)f2bf(wsrc[3]) << 16);
    w4.z = (unsigned int)f2bf(wsrc[4]) | ((unsigned int)f2bf(wsrc[5]) << 16);
    w4.w = (unsigned int)f2bf(wsrc[6]) | ((unsigned int)f2bf(wsrc[7]) << 16);
    ((uint4*)wlds)[fe] = w4;
  }
  __syncthreads();

  const int l = threadIdx.x & 63;
  const int row16 = l & 15, kg = l >> 4;
  const int wv = blockIdx.x * (FM_BLK / 64) + (threadIdx.x >> 6);
  const int nWv = gridDim.x * (FM_BLK / 64);
  float bias4[4];
#pragma unroll
  for (int n = 0; n < 4; ++n) bias4[n] = b[n * 16 + row16];

  const int nT = (U + 15) >> 4;
  for (int t = wv; t < nT; t += nWv) {
    const int u0 = t * 16;
    f32x4 acc0 = {0, 0, 0, 0}, acc1 = {0, 0, 0, 0};
    f32x4 acc2 = {0, 0, 0, 0}, acc3 = {0, 0, 0, 0};
    const int ua = min(u0 + row16, U - 1);  // clamped A-row user
#pragma unroll
    for (int h = 0; h < 2; ++h) {
      const size_t off = (size_t)ua * EDIM + h * 32 + kg * 8;
      short8 gfr = *(const short8*)(gbf + off);
      short8 sfr = *(const short8*)(sbf + off);
      short8 pfr = *(const short8*)(pbf + off);
      float gf[8], sf[8], pf[8];
#pragma unroll
      for (int j = 0; j < 8; ++j) {
        gf[j] = bf2f((unsigned short)gfr[j]);
        sf[j] = bf2f((unsigned short)sfr[j]);
        pf[j] = bf2f((unsigned short)pfr[j]);
      }
      short8 gs, gp, sp, gsp;
#pragma unroll
      for (int j = 0; j < 8; ++j) {
        const float a = gf[j] * sf[j];
        gs[j] = (short)f2bf(a);
        gp[j] = (short)f2bf(gf[j] * pf[j]);
        sp[j] = (short)f2bf(sf[j] * pf[j]);
        gsp[j] = (short)f2bf(a * pf[j]);
      }
      short8 afr[7] = {gfr, sfr, pfr, gs, gp, sp, gsp};
#pragma unroll
      for (int blk = 0; blk < 7; ++blk) {
        const int fb = blk * 512 + h * 256;
        const short8 b0 = *(const short8*)(wlds + (size_t)(fb + 0 * 64 + l) * 8);
        const short8 b1 = *(const short8*)(wlds + (size_t)(fb + 1 * 64 + l) * 8);
        const short8 b2 = *(const short8*)(wlds + (size_t)(fb + 2 * 64 + l) * 8);
        const short8 b3 = *(const short8*)(wlds + (size_t)(fb + 3 * 64 + l) * 8);
        acc0 = __builtin_amdgcn_mfma_f32_16x16x32_bf16(afr[blk], b0, acc0, 0, 0, 0);
        acc1 = __builtin_amdgcn_mfma_f32_16x16x32_bf16(afr[blk], b1, acc1, 0, 0, 0);
        acc2 = __builtin_amdgcn_mfma_f32_16x16x32_bf16(afr[blk], b2, acc2, 0, 0, 0);
        acc3 = __builtin_amdgcn_mfma_f32_16x16x32_bf16(afr[blk], b3, acc3, 0, 0, 0);
      }
    }
    // epilogue: me = acc + bias; hg = me + ue + me*ue
#pragma unroll
    for (int r = 0; r < 4; ++r) {
      const int u = u0 + kg * 4 + r;
      if (u < U) {
        const size_t ubase = (size_t)u * EDIM + row16;
        {
          const float me = acc0[r] + bias4[0];
          const float ue = uemb[ubase + 0];
          hg[ubase + 0] = me + ue + me * ue;
        }
        {
          const float me = acc1[r] + bias4[1];
          const float ue = uemb[ubase + 16];
          hg[ubase + 16] = me + ue + me * ue;
        }
        {
          const float me = acc2[r] + bias4[2];
          const float ue = uemb[ubase + 32];
          hg[ubase + 32] = me + ue + me * ue;
        }
        {
          const float me = acc3[r] + bias4[3];
          const float ue = uemb[ubase + 48];
          hg[ubase + 48] = me + ue + me * ue;
        }
      }
    }
  }
}

// ---------------------------------------------------------------------------
// Per-POI gather (transpose side), fused with mean: out = init + (L/2)*acc.
// ---------------------------------------------------------------------------
__global__ __launch_bounds__(256) void poi_gather_kernel(
    const int* __restrict__ ptrP, const int* __restrict__ permP,
    const int* __restrict__ rows, const float* __restrict__ pu_vals,
    const float* __restrict__ hg, const float* __restrict__ init,
    const int* __restrict__ num_layers, float* __restrict__ out, int P,
    int nnz) {
  const float scale = 0.5f * (float)num_layers[0];
  const int lane = threadIdx.x & 63;
  const int sub = lane >> 4, d4 = lane & 15;
  const int wv = blockIdx.x * 4 + (threadIdx.x >> 6);
  const int nW = gridDim.x * 4;
  for (int c = wv; c < P; c += nW) {
    const int start = ptrP[c];
    const int end = (c + 1 < P) ? ptrP[c + 1] : nnz;
    float4 a4 = {0, 0, 0, 0};
    for (int k0 = start; k0 < end; k0 += 64) {
      int r_v = 0;
      float v_v = 0.f;
      const int kk = k0 + lane;
      if (kk < end) {
        const int id = permP[kk];
        r_v = rows[id];
        v_v = pu_vals[id];
      }
      const int steps = (min(64, end - k0) + 3) >> 2;
      for (int t = 0; t < steps; ++t) {
        const int src = t * 4 + sub;
        const int rr = __shfl(r_v, src);
        const float vv = __shfl(v_v, src);
        const float4 h = ((const float4*)(hg + (size_t)rr * EDIM))[d4];
        a4.x += vv * h.x; a4.y += vv * h.y; a4.z += vv * h.z; a4.w += vv * h.w;
      }
    }
#pragma unroll
    for (int m = 16; m <= 32; m <<= 1) {
      a4.x += __shfl_xor(a4.x, m); a4.y += __shfl_xor(a4.y, m);
      a4.z += __shfl_xor(a4.z, m); a4.w += __shfl_xor(a4.w, m);
    }
    if (sub == 0) {
      const float4 iv = ((const float4*)(init + (size_t)c * EDIM))[d4];
      float4 o;
      o.x = iv.x + scale * a4.x;
      o.y = iv.y + scale * a4.y;
      o.z = iv.z + scale * a4.z;
      o.w = iv.w + scale * a4.w;
      ((float4*)(out + (size_t)c * EDIM))[d4] = o;
    }
  }
}

extern "C" void kernel_launch(void* const* d_in, const int* in_sizes, int n_in,
                              void* d_out, int out_size, void* d_ws,
                              size_t ws_size, hipStream_t stream) {
  const float* init = (const float*)d_in[0];
  const float* colp = (const float*)d_in[1];
  const float* geo = (const float*)d_in[2];
  const float* seq = (const float*)d_in[3];
  const float* uemb = (const float*)d_in[4];
  const int* up_rows = (const int*)d_in[5];
  const int* up_cols = (const int*)d_in[6];
  const float* up_vals = (const float*)d_in[7];
  const float* pu_vals = (const float*)d_in[8];
  const float* W = (const float*)d_in[9];
  const float* b = (const float*)d_in[10];
  const int* num_layers = (const int*)d_in[11];

  const int U = in_sizes[4] / EDIM;
  const int P = in_sizes[0] / EDIM;
  const int NNZ = in_sizes[5];

  int* ptrU = (int*)d_ws;             // U (counts -> exclusive offsets)
  int* ptrP = ptrU + U;               // P
  int2* csrU = (int2*)(ptrP + P);     // NNZ int2 (col, val_bits)
  int* permP = (int*)(csrU + NNZ);    // NNZ
  int* bsumU = permP + NNZ;           // 256
  int* bsumP = bsumU + 256;           // 256
  unsigned short* gbf = (unsigned short*)(bsumP + 256);  // U*64 bf16
  unsigned short* sbf = gbf + (size_t)U * EDIM;
  unsigned short* pbf = sbf + (size_t)U * EDIM;
  float* hg = (float*)(pbf + (size_t)U * EDIM);          // U*64 f32
  // rank arrays alias the g/s/p bf16 region (dead before user_gather writes)
  int* rankU = (int*)gbf;             // NNZ
  int* rankP = rankU + NNZ;           // NNZ
  float* out = (float*)d_out;

  const int nbU = (U + SCAN_CHUNK - 1) / SCAN_CHUNK;
  const int nbP = (P + SCAN_CHUNK - 1) / SCAN_CHUNK;
  const int nb4 = (NNZ / 4 + 255) / 256 + 1;  // threads of 4 nnz each (+tail)

  hipMemsetAsync(ptrU, 0, (size_t)(U + P) * sizeof(int), stream);

  hist_rank_kernel<<<nb4, 256, 0, stream>>>(up_rows, up_cols, ptrU, ptrP,
                                            rankU, rankP, NNZ);

  scan_reduce_kernel<<<nbU, SCAN_BLK, 0, stream>>>(ptrU, U, bsumU);
  scan_reduce_kernel<<<nbP, SCAN_BLK, 0, stream>>>(ptrP, P, bsumP);
  scan_top_kernel<<<1, 256, 0, stream>>>(bsumU, nbU);
  scan_top_kernel<<<1, 256, 0, stream>>>(bsumP, nbP);
  scan_apply_kernel<<<nbU, SCAN_BLK, 0, stream>>>(ptrU, U, bsumU);
  scan_apply_kernel<<<nbP, SCAN_BLK, 0, stream>>>(ptrP, P, bsumP);

  scatter_kernel<<<nb4, 256, 0, stream>>>(up_rows, up_cols, up_vals, ptrU,
                                          ptrP, rankU, rankP, csrU, permP,
                                          NNZ);

  user_gather_kernel<<<2048, 256, 0, stream>>>(ptrU, csrU, geo, seq, colp,
                                               gbf, sbf, pbf, U, NNZ);

  fusion_mfma_kernel<<<512, FM_BLK, 0, stream>>>(gbf, sbf, pbf, uemb, W, b,
                                                 hg, U);

  poi_gather_kernel<<<2048, 256, 0, stream>>>(ptrP, permP, up_rows, pu_vals,
                                              hg, init, num_layers, out, P,
                                              NNZ);
}

// Round 7
// 557.693 us; speedup vs baseline: 2.3154x; 1.2477x over previous
//
#include <hip/hip_runtime.h>

#define EDIM 64
#define SCAN_BLK 256
#define SCAN_CHUNK 2048  // 8 elements per thread

typedef __attribute__((ext_vector_type(8))) short short8;
typedef __attribute__((ext_vector_type(4))) float f32x4;

// f32 -> bf16 round-to-nearest-even
__device__ __forceinline__ unsigned int f2bf(float x) {
  unsigned int u = __float_as_uint(x);
  u += 0x7FFFu + ((u >> 16) & 1u);
  return u >> 16;
}
__device__ __forceinline__ float bf2f(unsigned short s) {
  return __uint_as_float(((unsigned int)s) << 16);
}
__device__ __forceinline__ float bflo(unsigned int u) {
  return __uint_as_float(u << 16);
}
__device__ __forceinline__ float bfhi(unsigned int u) {
  return __uint_as_float(u & 0xFFFF0000u);
}

// ---------------------------------------------------------------------------
// f32 -> bf16 table conversion (3 tables in one launch).
// ---------------------------------------------------------------------------
__global__ __launch_bounds__(256) void tobf16_kernel(
    const float4* __restrict__ s0, const float4* __restrict__ s1,
    const float4* __restrict__ s2, uint2* __restrict__ d0,
    uint2* __restrict__ d1, uint2* __restrict__ d2, int n4) {
  const int stride = gridDim.x * blockDim.x;
  for (int i = blockIdx.x * blockDim.x + threadIdx.x; i < 3 * n4; i += stride) {
    const int t = i / n4, j = i - t * n4;
    const float4* s = (t == 0) ? s0 : ((t == 1) ? s1 : s2);
    uint2* d = (t == 0) ? d0 : ((t == 1) ? d1 : d2);
    const float4 v = s[j];
    uint2 o;
    o.x = f2bf(v.x) | (f2bf(v.y) << 16);
    o.y = f2bf(v.z) | (f2bf(v.w) << 16);
    d[j] = o;
  }
}

// ---------------------------------------------------------------------------
// Histogram with rank capture: rank[i] = old count.
// ---------------------------------------------------------------------------
__global__ __launch_bounds__(256) void hist_rank_kernel(
    const int* __restrict__ rows, const int* __restrict__ cols,
    int* __restrict__ cntU, int* __restrict__ cntP,
    int* __restrict__ rankU, int* __restrict__ rankP, int nnz) {
  const int t = blockIdx.x * blockDim.x + threadIdx.x;
  const int i0 = t * 4;
  if (i0 + 3 < nnz) {
    const int4 r = ((const int4*)rows)[t];
    const int4 c = ((const int4*)cols)[t];
    int4 ru, rp;
    ru.x = atomicAdd(&cntU[r.x], 1);
    ru.y = atomicAdd(&cntU[r.y], 1);
    ru.z = atomicAdd(&cntU[r.z], 1);
    ru.w = atomicAdd(&cntU[r.w], 1);
    rp.x = atomicAdd(&cntP[c.x], 1);
    rp.y = atomicAdd(&cntP[c.y], 1);
    rp.z = atomicAdd(&cntP[c.z], 1);
    rp.w = atomicAdd(&cntP[c.w], 1);
    ((int4*)rankU)[t] = ru;
    ((int4*)rankP)[t] = rp;
  } else {
    for (int i = i0; i < nnz; ++i) {
      rankU[i] = atomicAdd(&cntU[rows[i]], 1);
      rankP[i] = atomicAdd(&cntP[cols[i]], 1);
    }
  }
}

// ---------------------------------------------------------------------------
// Hierarchical exclusive scan (unchanged).
// ---------------------------------------------------------------------------
__global__ __launch_bounds__(SCAN_BLK) void scan_reduce_kernel(
    const int* __restrict__ cnt, int n, int* __restrict__ bsum) {
  __shared__ int wsh[SCAN_BLK / 64];
  const int lane = threadIdx.x & 63, wid = threadIdx.x >> 6;
  const int base = blockIdx.x * SCAN_CHUNK + threadIdx.x * 8;
  int s = 0;
#pragma unroll
  for (int k = 0; k < 8; ++k) {
    const int idx = base + k;
    if (idx < n) s += cnt[idx];
  }
  for (int d = 32; d; d >>= 1) s += __shfl_down(s, d);
  if (lane == 0) wsh[wid] = s;
  __syncthreads();
  if (threadIdx.x == 0) {
    int t = 0;
    for (int w = 0; w < SCAN_BLK / 64; ++w) t += wsh[w];
    bsum[blockIdx.x] = t;
  }
}

__global__ void scan_top_kernel(int* __restrict__ bsum, int nb) {
  __shared__ int tmp[256];
  if ((int)threadIdx.x < nb) tmp[threadIdx.x] = bsum[threadIdx.x];
  __syncthreads();
  if (threadIdx.x == 0) {
    int run = 0;
    for (int i = 0; i < nb; ++i) { const int c = tmp[i]; tmp[i] = run; run += c; }
  }
  __syncthreads();
  if ((int)threadIdx.x < nb) bsum[threadIdx.x] = tmp[threadIdx.x];
}

__global__ __launch_bounds__(SCAN_BLK) void scan_apply_kernel(
    int* __restrict__ ptr, int n, const int* __restrict__ bsum) {
  __shared__ int wsum[SCAN_BLK / 64];
  const int lane = threadIdx.x & 63, wid = threadIdx.x >> 6;
  const int base = blockIdx.x * SCAN_CHUNK + threadIdx.x * 8;
  int v[8];
  int tot = 0;
#pragma unroll
  for (int k = 0; k < 8; ++k) {
    const int idx = base + k;
    v[k] = (idx < n) ? ptr[idx] : 0;
    tot += v[k];
  }
  int sc = tot;  // inclusive wave scan
  for (int d = 1; d < 64; d <<= 1) {
    const int o = __shfl_up(sc, d);
    if (lane >= d) sc += o;
  }
  if (lane == 63) wsum[wid] = sc;
  __syncthreads();
  int woff = 0;
  for (int w = 0; w < wid; ++w) woff += wsum[w];
  int run = bsum[blockIdx.x] + woff + sc - tot;  // exclusive offset
#pragma unroll
  for (int k = 0; k < 8; ++k) {
    const int idx = base + k;
    if (idx < n) ptr[idx] = run;
    run += v[k];
  }
}

// ---------------------------------------------------------------------------
// Atomic-free scatter: pos = ptr[key] + rank. Both sides store direct data:
// csrU[pos] = {col, up_val}; csrP[pos] = {row, pu_val}.
// ---------------------------------------------------------------------------
__global__ __launch_bounds__(256) void scatter_kernel(
    const int* __restrict__ rows, const int* __restrict__ cols,
    const float* __restrict__ up_vals, const float* __restrict__ pu_vals,
    const int* __restrict__ ptrU, const int* __restrict__ ptrP,
    const int* __restrict__ rankU, const int* __restrict__ rankP,
    int2* __restrict__ csrU, int2* __restrict__ csrP, int nnz) {
  const int t = blockIdx.x * blockDim.x + threadIdx.x;
  const int i0 = t * 4;
  if (i0 + 3 < nnz) {
    const int4 r = ((const int4*)rows)[t];
    const int4 c = ((const int4*)cols)[t];
    const float4 v = ((const float4*)up_vals)[t];
    const float4 pv = ((const float4*)pu_vals)[t];
    const int4 ru = ((const int4*)rankU)[t];
    const int4 rp = ((const int4*)rankP)[t];
    const int pu0 = ptrU[r.x] + ru.x;
    const int pu1 = ptrU[r.y] + ru.y;
    const int pu2 = ptrU[r.z] + ru.z;
    const int pu3 = ptrU[r.w] + ru.w;
    const int pp0 = ptrP[c.x] + rp.x;
    const int pp1 = ptrP[c.y] + rp.y;
    const int pp2 = ptrP[c.z] + rp.z;
    const int pp3 = ptrP[c.w] + rp.w;
    csrU[pu0] = make_int2(c.x, __float_as_int(v.x));
    csrU[pu1] = make_int2(c.y, __float_as_int(v.y));
    csrU[pu2] = make_int2(c.z, __float_as_int(v.z));
    csrU[pu3] = make_int2(c.w, __float_as_int(v.w));
    csrP[pp0] = make_int2(r.x, __float_as_int(pv.x));
    csrP[pp1] = make_int2(r.y, __float_as_int(pv.y));
    csrP[pp2] = make_int2(r.z, __float_as_int(pv.z));
    csrP[pp3] = make_int2(r.w, __float_as_int(pv.w));
  } else {
    for (int i = i0; i < nnz; ++i) {
      const int rr = rows[i], cc = cols[i];
      csrU[ptrU[rr] + rankU[i]] = make_int2(cc, __float_as_int(up_vals[i]));
      csrP[ptrP[cc] + rankP[i]] = make_int2(rr, __float_as_int(pu_vals[i]));
    }
  }
}

// ---------------------------------------------------------------------------
// Per-user gather over bf16 tables -> bf16 g/s/p outputs [U][64].
// lane = (sub = lane>>4, d4 = lane&15); 4 nnz per step; 8 B loads per table.
// ---------------------------------------------------------------------------
__global__ __launch_bounds__(256) void user_gather_kernel(
    const int* __restrict__ ptrU, const int2* __restrict__ csrU,
    const unsigned short* __restrict__ tblG,
    const unsigned short* __restrict__ tblS,
    const unsigned short* __restrict__ tblC,
    unsigned short* __restrict__ gw, unsigned short* __restrict__ sw,
    unsigned short* __restrict__ pw, int U, int nnz) {
  const int lane = threadIdx.x & 63;
  const int sub = lane >> 4, d4 = lane & 15;
  const int wv = blockIdx.x * 4 + (threadIdx.x >> 6);
  const int nW = gridDim.x * 4;
  for (int u = wv; u < U; u += nW) {
    const int start = ptrU[u];
    const int end = (u + 1 < U) ? ptrU[u + 1] : nnz;
    float4 g4 = {0, 0, 0, 0}, s4 = {0, 0, 0, 0}, p4 = {0, 0, 0, 0};
    for (int k0 = start; k0 < end; k0 += 64) {
      int c_v = 0;
      float v_v = 0.f;
      const int kk = k0 + lane;
      if (kk < end) {
        const int2 e = csrU[kk];
        c_v = e.x;
        v_v = __int_as_float(e.y);
      }
      const int steps = (min(64, end - k0) + 3) >> 2;
      for (int t = 0; t < steps; ++t) {
        const int src = t * 4 + sub;
        const int cc = __shfl(c_v, src);
        const float vv = __shfl(v_v, src);
        const size_t rb = (size_t)cc * EDIM;
        const uint2 gg = ((const uint2*)(tblG + rb))[d4];
        const uint2 ss = ((const uint2*)(tblS + rb))[d4];
        const uint2 pp = ((const uint2*)(tblC + rb))[d4];
        g4.x += vv * bflo(gg.x); g4.y += vv * bfhi(gg.x);
        g4.z += vv * bflo(gg.y); g4.w += vv * bfhi(gg.y);
        s4.x += vv * bflo(ss.x); s4.y += vv * bfhi(ss.x);
        s4.z += vv * bflo(ss.y); s4.w += vv * bfhi(ss.y);
        p4.x += vv * bflo(pp.x); p4.y += vv * bfhi(pp.x);
        p4.z += vv * bflo(pp.y); p4.w += vv * bfhi(pp.y);
      }
    }
#pragma unroll
    for (int m = 16; m <= 32; m <<= 1) {
      g4.x += __shfl_xor(g4.x, m); g4.y += __shfl_xor(g4.y, m);
      g4.z += __shfl_xor(g4.z, m); g4.w += __shfl_xor(g4.w, m);
      s4.x += __shfl_xor(s4.x, m); s4.y += __shfl_xor(s4.y, m);
      s4.z += __shfl_xor(s4.z, m); s4.w += __shfl_xor(s4.w, m);
      p4.x += __shfl_xor(p4.x, m); p4.y += __shfl_xor(p4.y, m);
      p4.z += __shfl_xor(p4.z, m); p4.w += __shfl_xor(p4.w, m);
    }
    if (sub == 0) {
      uint2 gp2, sp2, pp2;
      gp2.x = f2bf(g4.x) | (f2bf(g4.y) << 16);
      gp2.y = f2bf(g4.z) | (f2bf(g4.w) << 16);
      sp2.x = f2bf(s4.x) | (f2bf(s4.y) << 16);
      sp2.y = f2bf(s4.z) | (f2bf(s4.w) << 16);
      pp2.x = f2bf(p4.x) | (f2bf(p4.y) << 16);
      pp2.y = f2bf(p4.z) | (f2bf(p4.w) << 16);
      ((uint2*)(gw + (size_t)u * EDIM))[d4] = gp2;
      ((uint2*)(sw + (size_t)u * EDIM))[d4] = sp2;
      ((uint2*)(pw + (size_t)u * EDIM))[d4] = pp2;
    }
  }
}

// ---------------------------------------------------------------------------
// Fusion as bf16 MFMA GEMM: msg[U,448] @ W^T[448,64] + bias + gated merge.
// Outputs hg as bf16.
// ---------------------------------------------------------------------------
#define FM_BLK 256
__global__ __launch_bounds__(FM_BLK) void fusion_mfma_kernel(
    const unsigned short* __restrict__ gbf, const unsigned short* __restrict__ sbf,
    const unsigned short* __restrict__ pbf, const float* __restrict__ uemb,
    const float* __restrict__ W, const float* __restrict__ b,
    unsigned short* __restrict__ hbf, int U) {
  __shared__ unsigned short wlds[7 * 2 * 4 * 64 * 8];  // 57344 B
  for (int fe = threadIdx.x; fe < 7 * 2 * 4 * 64; fe += FM_BLK) {
    const int ln = fe & 63;
    const int n = (fe >> 6) & 3;
    const int h = (fe >> 8) & 1;
    const int blk = fe >> 9;
    const int e = n * 16 + (ln & 15);
    const int f0 = blk * 64 + h * 32 + (ln >> 4) * 8;
    const float* wsrc = W + (size_t)e * 448 + f0;
    uint4 w4;
    w4.x = f2bf(wsrc[0]) | (f2bf(wsrc[1]) << 16);
    w4.y = f2bf(wsrc[2]) | (f2bf(wsrc[3]) << 16);
    w4.z = f2bf(wsrc[4]) | (f2bf(wsrc[5]) << 16);
    w4.w = f2bf(wsrc[6]) | (f2bf(wsrc[7]) << 16);
    ((uint4*)wlds)[fe] = w4;
  }
  __syncthreads();

  const int l = threadIdx.x & 63;
  const int row16 = l & 15, kg = l >> 4;
  const int wv = blockIdx.x * (FM_BLK / 64) + (threadIdx.x >> 6);
  const int nWv = gridDim.x * (FM_BLK / 64);
  float bias4[4];
#pragma unroll
  for (int n = 0; n < 4; ++n) bias4[n] = b[n * 16 + row16];

  const int nT = (U + 15) >> 4;
  for (int t = wv; t < nT; t += nWv) {
    const int u0 = t * 16;
    f32x4 acc0 = {0, 0, 0, 0}, acc1 = {0, 0, 0, 0};
    f32x4 acc2 = {0, 0, 0, 0}, acc3 = {0, 0, 0, 0};
    const int ua = min(u0 + row16, U - 1);  // clamped A-row user
#pragma unroll
    for (int h = 0; h < 2; ++h) {
      const size_t off = (size_t)ua * EDIM + h * 32 + kg * 8;
      short8 gfr = *(const short8*)(gbf + off);
      short8 sfr = *(const short8*)(sbf + off);
      short8 pfr = *(const short8*)(pbf + off);
      float gf[8], sf[8], pf[8];
#pragma unroll
      for (int j = 0; j < 8; ++j) {
        gf[j] = bf2f((unsigned short)gfr[j]);
        sf[j] = bf2f((unsigned short)sfr[j]);
        pf[j] = bf2f((unsigned short)pfr[j]);
      }
      short8 gs, gp, sp, gsp;
#pragma unroll
      for (int j = 0; j < 8; ++j) {
        const float a = gf[j] * sf[j];
        gs[j] = (short)f2bf(a);
        gp[j] = (short)f2bf(gf[j] * pf[j]);
        sp[j] = (short)f2bf(sf[j] * pf[j]);
        gsp[j] = (short)f2bf(a * pf[j]);
      }
      short8 afr[7] = {gfr, sfr, pfr, gs, gp, sp, gsp};
#pragma unroll
      for (int blk = 0; blk < 7; ++blk) {
        const int fb = blk * 512 + h * 256;
        const short8 b0 = *(const short8*)(wlds + (size_t)(fb + 0 * 64 + l) * 8);
        const short8 b1 = *(const short8*)(wlds + (size_t)(fb + 1 * 64 + l) * 8);
        const short8 b2 = *(const short8*)(wlds + (size_t)(fb + 2 * 64 + l) * 8);
        const short8 b3 = *(const short8*)(wlds + (size_t)(fb + 3 * 64 + l) * 8);
        acc0 = __builtin_amdgcn_mfma_f32_16x16x32_bf16(afr[blk], b0, acc0, 0, 0, 0);
        acc1 = __builtin_amdgcn_mfma_f32_16x16x32_bf16(afr[blk], b1, acc1, 0, 0, 0);
        acc2 = __builtin_amdgcn_mfma_f32_16x16x32_bf16(afr[blk], b2, acc2, 0, 0, 0);
        acc3 = __builtin_amdgcn_mfma_f32_16x16x32_bf16(afr[blk], b3, acc3, 0, 0, 0);
      }
    }
    // epilogue: me = acc + bias; hg = me + ue + me*ue  (bf16 out)
#pragma unroll
    for (int r = 0; r < 4; ++r) {
      const int u = u0 + kg * 4 + r;
      if (u < U) {
        const size_t ubase = (size_t)u * EDIM + row16;
        {
          const float me = acc0[r] + bias4[0];
          const float ue = uemb[ubase + 0];
          hbf[ubase + 0] = (unsigned short)f2bf(me + ue + me * ue);
        }
        {
          const float me = acc1[r] + bias4[1];
          const float ue = uemb[ubase + 16];
          hbf[ubase + 16] = (unsigned short)f2bf(me + ue + me * ue);
        }
        {
          const float me = acc2[r] + bias4[2];
          const float ue = uemb[ubase + 32];
          hbf[ubase + 32] = (unsigned short)f2bf(me + ue + me * ue);
        }
        {
          const float me = acc3[r] + bias4[3];
          const float ue = uemb[ubase + 48];
          hbf[ubase + 48] = (unsigned short)f2bf(me + ue + me * ue);
        }
      }
    }
  }
}

// ---------------------------------------------------------------------------
// Per-POI gather over bf16 hg, direct csrP = {row, pu_val}, fused mean:
// out = init + (L/2)*acc.
// ---------------------------------------------------------------------------
__global__ __launch_bounds__(256) void poi_gather_kernel(
    const int* __restrict__ ptrP, const int2* __restrict__ csrP,
    const unsigned short* __restrict__ hbf, const float* __restrict__ init,
    const int* __restrict__ num_layers, float* __restrict__ out, int P,
    int nnz) {
  const float scale = 0.5f * (float)num_layers[0];
  const int lane = threadIdx.x & 63;
  const int sub = lane >> 4, d4 = lane & 15;
  const int wv = blockIdx.x * 4 + (threadIdx.x >> 6);
  const int nW = gridDim.x * 4;
  for (int c = wv; c < P; c += nW) {
    const int start = ptrP[c];
    const int end = (c + 1 < P) ? ptrP[c + 1] : nnz;
    float4 a4 = {0, 0, 0, 0};
    for (int k0 = start; k0 < end; k0 += 64) {
      int r_v = 0;
      float v_v = 0.f;
      const int kk = k0 + lane;
      if (kk < end) {
        const int2 e = csrP[kk];
        r_v = e.x;
        v_v = __int_as_float(e.y);
      }
      const int steps = (min(64, end - k0) + 3) >> 2;
      for (int t = 0; t < steps; ++t) {
        const int src = t * 4 + sub;
        const int rr = __shfl(r_v, src);
        const float vv = __shfl(v_v, src);
        const uint2 hh = ((const uint2*)(hbf + (size_t)rr * EDIM))[d4];
        a4.x += vv * bflo(hh.x); a4.y += vv * bfhi(hh.x);
        a4.z += vv * bflo(hh.y); a4.w += vv * bfhi(hh.y);
      }
    }
#pragma unroll
    for (int m = 16; m <= 32; m <<= 1) {
      a4.x += __shfl_xor(a4.x, m); a4.y += __shfl_xor(a4.y, m);
      a4.z += __shfl_xor(a4.z, m); a4.w += __shfl_xor(a4.w, m);
    }
    if (sub == 0) {
      const float4 iv = ((const float4*)(init + (size_t)c * EDIM))[d4];
      float4 o;
      o.x = iv.x + scale * a4.x;
      o.y = iv.y + scale * a4.y;
      o.z = iv.z + scale * a4.z;
      o.w = iv.w + scale * a4.w;
      ((float4*)(out + (size_t)c * EDIM))[d4] = o;
    }
  }
}

extern "C" void kernel_launch(void* const* d_in, const int* in_sizes, int n_in,
                              void* d_out, int out_size, void* d_ws,
                              size_t ws_size, hipStream_t stream) {
  const float* init = (const float*)d_in[0];
  const float* colp = (const float*)d_in[1];
  const float* geo = (const float*)d_in[2];
  const float* seq = (const float*)d_in[3];
  const float* uemb = (const float*)d_in[4];
  const int* up_rows = (const int*)d_in[5];
  const int* up_cols = (const int*)d_in[6];
  const float* up_vals = (const float*)d_in[7];
  const float* pu_vals = (const float*)d_in[8];
  const float* W = (const float*)d_in[9];
  const float* b = (const float*)d_in[10];
  const int* num_layers = (const int*)d_in[11];

  const int U = in_sizes[4] / EDIM;
  const int P = in_sizes[0] / EDIM;
  const int NNZ = in_sizes[5];

  // ---- workspace layout (peak ~97.7 MB) ----
  int* ptrU = (int*)d_ws;                     // U
  int* ptrP = ptrU + U;                       // P
  int* bsumU = ptrP + P;                      // 256
  int* bsumP = bsumU + 256;                   // 256
  int2* csrU = (int2*)(bsumP + 256);          // NNZ {col, up_val}
  int2* csrP = csrU + NNZ;                    // NNZ {row, pu_val}
  unsigned short* tblS = (unsigned short*)(csrP + NNZ);  // P*64 bf16 (25.6 MB)
  unsigned short* hbf = tblS;                 // U*64 bf16, aliases tblS (dead)
  unsigned short* gbf = tblS + (size_t)P * EDIM;         // U*64 bf16
  unsigned short* sbf = gbf + (size_t)U * EDIM;
  unsigned short* pbf = sbf + (size_t)U * EDIM;
  int* rankU = (int*)gbf;                     // NNZ, aliases gbf/sbf (dead
  int* rankP = rankU + NNZ;                   //   before user_gather writes)
  // d_out doubles as scratch for two bf16 tables (dead before final write)
  unsigned short* tblG = (unsigned short*)d_out;          // P*64 bf16
  unsigned short* tblC = tblG + (size_t)P * EDIM;         // P*64 bf16
  float* out = (float*)d_out;

  const int nbU = (U + SCAN_CHUNK - 1) / SCAN_CHUNK;
  const int nbP = (P + SCAN_CHUNK - 1) / SCAN_CHUNK;
  const int nb4 = (NNZ / 4 + 255) / 256 + 1;  // threads of 4 nnz each (+tail)

  hipMemsetAsync(ptrU, 0, (size_t)(U + P) * sizeof(int), stream);

  tobf16_kernel<<<2048, 256, 0, stream>>>(
      (const float4*)geo, (const float4*)seq, (const float4*)colp,
      (uint2*)tblG, (uint2*)tblS, (uint2*)tblC, P * (EDIM / 4));

  hist_rank_kernel<<<nb4, 256, 0, stream>>>(up_rows, up_cols, ptrU, ptrP,
                                            rankU, rankP, NNZ);

  scan_reduce_kernel<<<nbU, SCAN_BLK, 0, stream>>>(ptrU, U, bsumU);
  scan_reduce_kernel<<<nbP, SCAN_BLK, 0, stream>>>(ptrP, P, bsumP);
  scan_top_kernel<<<1, 256, 0, stream>>>(bsumU, nbU);
  scan_top_kernel<<<1, 256, 0, stream>>>(bsumP, nbP);
  scan_apply_kernel<<<nbU, SCAN_BLK, 0, stream>>>(ptrU, U, bsumU);
  scan_apply_kernel<<<nbP, SCAN_BLK, 0, stream>>>(ptrP, P, bsumP);

  scatter_kernel<<<nb4, 256, 0, stream>>>(up_rows, up_cols, up_vals, pu_vals,
                                          ptrU, ptrP, rankU, rankP, csrU,
                                          csrP, NNZ);

  user_gather_kernel<<<2048, 256, 0, stream>>>(ptrU, csrU, tblG, tblS, tblC,
                                               gbf, sbf, pbf, U, NNZ);

  fusion_mfma_kernel<<<512, FM_BLK, 0, stream>>>(gbf, sbf, pbf, uemb, W, b,
                                                 hbf, U);

  poi_gather_kernel<<<2048, 256, 0, stream>>>(ptrP, csrP, hbf, init,
                                              num_layers, out, P, NNZ);
}

// Round 8
// 549.358 us; speedup vs baseline: 2.3506x; 1.0152x over previous
//
#include <hip/hip_runtime.h>

#define EDIM 64
#define SCAN_BLK 256
#define SCAN_CHUNK 2048  // 8 elements per thread
#define CSTRIDE 4        // counter padding: one counter per 16 B

typedef __attribute__((ext_vector_type(8))) short short8;
typedef __attribute__((ext_vector_type(4))) float f32x4;

// f32 -> bf16 round-to-nearest-even
__device__ __forceinline__ unsigned int f2bf(float x) {
  unsigned int u = __float_as_uint(x);
  u += 0x7FFFu + ((u >> 16) & 1u);
  return u >> 16;
}
__device__ __forceinline__ float bf2f(unsigned short s) {
  return __uint_as_float(((unsigned int)s) << 16);
}
__device__ __forceinline__ float bflo(unsigned int u) {
  return __uint_as_float(u << 16);
}
__device__ __forceinline__ float bfhi(unsigned int u) {
  return __uint_as_float(u & 0xFFFF0000u);
}

// ---------------------------------------------------------------------------
// f32 -> bf16 table conversion (3 tables in one launch).
// ---------------------------------------------------------------------------
__global__ __launch_bounds__(256) void tobf16_kernel(
    const float4* __restrict__ s0, const float4* __restrict__ s1,
    const float4* __restrict__ s2, uint2* __restrict__ d0,
    uint2* __restrict__ d1, uint2* __restrict__ d2, int n4) {
  const int stride = gridDim.x * blockDim.x;
  for (int i = blockIdx.x * blockDim.x + threadIdx.x; i < 3 * n4; i += stride) {
    const int t = i / n4, j = i - t * n4;
    const float4* s = (t == 0) ? s0 : ((t == 1) ? s1 : s2);
    uint2* d = (t == 0) ? d0 : ((t == 1) ? d1 : d2);
    const float4 v = s[j];
    uint2 o;
    o.x = f2bf(v.x) | (f2bf(v.y) << 16);
    o.y = f2bf(v.z) | (f2bf(v.w) << 16);
    d[j] = o;
  }
}

// ---------------------------------------------------------------------------
// Histogram with rank capture on PADDED counters (stride 16 B) to break
// same-cache-line atomic serialization. rank[i] = old count.
// ---------------------------------------------------------------------------
__global__ __launch_bounds__(256) void hist_rank_kernel(
    const int* __restrict__ rows, const int* __restrict__ cols,
    int* __restrict__ cntU, int* __restrict__ cntP,
    int* __restrict__ rankU, int* __restrict__ rankP, int nnz) {
  const int t = blockIdx.x * blockDim.x + threadIdx.x;
  const int i0 = t * 4;
  if (i0 + 3 < nnz) {
    const int4 r = ((const int4*)rows)[t];
    const int4 c = ((const int4*)cols)[t];
    int4 ru, rp;
    ru.x = atomicAdd(&cntU[r.x << 2], 1);
    ru.y = atomicAdd(&cntU[r.y << 2], 1);
    ru.z = atomicAdd(&cntU[r.z << 2], 1);
    ru.w = atomicAdd(&cntU[r.w << 2], 1);
    rp.x = atomicAdd(&cntP[c.x << 2], 1);
    rp.y = atomicAdd(&cntP[c.y << 2], 1);
    rp.z = atomicAdd(&cntP[c.z << 2], 1);
    rp.w = atomicAdd(&cntP[c.w << 2], 1);
    ((int4*)rankU)[t] = ru;
    ((int4*)rankP)[t] = rp;
  } else {
    for (int i = i0; i < nnz; ++i) {
      rankU[i] = atomicAdd(&cntU[rows[i] << 2], 1);
      rankP[i] = atomicAdd(&cntP[cols[i] << 2], 1);
    }
  }
}

// ---------------------------------------------------------------------------
// Hierarchical exclusive scan over STRIDED counters -> COMPACT ptr array.
// ---------------------------------------------------------------------------
__global__ __launch_bounds__(SCAN_BLK) void scan_reduce_kernel(
    const int* __restrict__ cnt4, int n, int* __restrict__ bsum) {
  __shared__ int wsh[SCAN_BLK / 64];
  const int lane = threadIdx.x & 63, wid = threadIdx.x >> 6;
  const int base = blockIdx.x * SCAN_CHUNK + threadIdx.x * 8;
  int s = 0;
#pragma unroll
  for (int k = 0; k < 8; ++k) {
    const int idx = base + k;
    if (idx < n) s += cnt4[idx << 2];
  }
  for (int d = 32; d; d >>= 1) s += __shfl_down(s, d);
  if (lane == 0) wsh[wid] = s;
  __syncthreads();
  if (threadIdx.x == 0) {
    int t = 0;
    for (int w = 0; w < SCAN_BLK / 64; ++w) t += wsh[w];
    bsum[blockIdx.x] = t;
  }
}

__global__ void scan_top_kernel(int* __restrict__ bsum, int nb) {
  __shared__ int tmp[256];
  if ((int)threadIdx.x < nb) tmp[threadIdx.x] = bsum[threadIdx.x];
  __syncthreads();
  if (threadIdx.x == 0) {
    int run = 0;
    for (int i = 0; i < nb; ++i) { const int c = tmp[i]; tmp[i] = run; run += c; }
  }
  __syncthreads();
  if ((int)threadIdx.x < nb) bsum[threadIdx.x] = tmp[threadIdx.x];
}

__global__ __launch_bounds__(SCAN_BLK) void scan_apply_kernel(
    const int* __restrict__ cnt4, int* __restrict__ ptr, int n,
    const int* __restrict__ bsum) {
  __shared__ int wsum[SCAN_BLK / 64];
  const int lane = threadIdx.x & 63, wid = threadIdx.x >> 6;
  const int base = blockIdx.x * SCAN_CHUNK + threadIdx.x * 8;
  int v[8];
  int tot = 0;
#pragma unroll
  for (int k = 0; k < 8; ++k) {
    const int idx = base + k;
    v[k] = (idx < n) ? cnt4[idx << 2] : 0;
    tot += v[k];
  }
  int sc = tot;  // inclusive wave scan
  for (int d = 1; d < 64; d <<= 1) {
    const int o = __shfl_up(sc, d);
    if (lane >= d) sc += o;
  }
  if (lane == 63) wsum[wid] = sc;
  __syncthreads();
  int woff = 0;
  for (int w = 0; w < wid; ++w) woff += wsum[w];
  int run = bsum[blockIdx.x] + woff + sc - tot;  // exclusive offset
#pragma unroll
  for (int k = 0; k < 8; ++k) {
    const int idx = base + k;
    if (idx < n) ptr[idx] = run;
    run += v[k];
  }
}

// ---------------------------------------------------------------------------
// Atomic-free scatter: pos = ptr[key] + rank. Both sides store direct data:
// csrU[pos] = {col, up_val}; csrP[pos] = {row, pu_val}.
// ---------------------------------------------------------------------------
__global__ __launch_bounds__(256) void scatter_kernel(
    const int* __restrict__ rows, const int* __restrict__ cols,
    const float* __restrict__ up_vals, const float* __restrict__ pu_vals,
    const int* __restrict__ ptrU, const int* __restrict__ ptrP,
    const int* __restrict__ rankU, const int* __restrict__ rankP,
    int2* __restrict__ csrU, int2* __restrict__ csrP, int nnz) {
  const int t = blockIdx.x * blockDim.x + threadIdx.x;
  const int i0 = t * 4;
  if (i0 + 3 < nnz) {
    const int4 r = ((const int4*)rows)[t];
    const int4 c = ((const int4*)cols)[t];
    const float4 v = ((const float4*)up_vals)[t];
    const float4 pv = ((const float4*)pu_vals)[t];
    const int4 ru = ((const int4*)rankU)[t];
    const int4 rp = ((const int4*)rankP)[t];
    const int pu0 = ptrU[r.x] + ru.x;
    const int pu1 = ptrU[r.y] + ru.y;
    const int pu2 = ptrU[r.z] + ru.z;
    const int pu3 = ptrU[r.w] + ru.w;
    const int pp0 = ptrP[c.x] + rp.x;
    const int pp1 = ptrP[c.y] + rp.y;
    const int pp2 = ptrP[c.z] + rp.z;
    const int pp3 = ptrP[c.w] + rp.w;
    csrU[pu0] = make_int2(c.x, __float_as_int(v.x));
    csrU[pu1] = make_int2(c.y, __float_as_int(v.y));
    csrU[pu2] = make_int2(c.z, __float_as_int(v.z));
    csrU[pu3] = make_int2(c.w, __float_as_int(v.w));
    csrP[pp0] = make_int2(r.x, __float_as_int(pv.x));
    csrP[pp1] = make_int2(r.y, __float_as_int(pv.y));
    csrP[pp2] = make_int2(r.z, __float_as_int(pv.z));
    csrP[pp3] = make_int2(r.w, __float_as_int(pv.w));
  } else {
    for (int i = i0; i < nnz; ++i) {
      const int rr = rows[i], cc = cols[i];
      csrU[ptrU[rr] + rankU[i]] = make_int2(cc, __float_as_int(up_vals[i]));
      csrP[ptrP[cc] + rankP[i]] = make_int2(rr, __float_as_int(pu_vals[i]));
    }
  }
}

// ---------------------------------------------------------------------------
// Per-user gather over bf16 tables -> bf16 g/s/p outputs [U][64].
// lane = (sub = lane>>4, d4 = lane&15); 4 nnz per step; 8 B loads per table.
// ---------------------------------------------------------------------------
__global__ __launch_bounds__(256) void user_gather_kernel(
    const int* __restrict__ ptrU, const int2* __restrict__ csrU,
    const unsigned short* __restrict__ tblG,
    const unsigned short* __restrict__ tblS,
    const unsigned short* __restrict__ tblC,
    unsigned short* __restrict__ gw, unsigned short* __restrict__ sw,
    unsigned short* __restrict__ pw, int U, int nnz) {
  const int lane = threadIdx.x & 63;
  const int sub = lane >> 4, d4 = lane & 15;
  const int wv = blockIdx.x * 4 + (threadIdx.x >> 6);
  const int nW = gridDim.x * 4;
  for (int u = wv; u < U; u += nW) {
    const int start = ptrU[u];
    const int end = (u + 1 < U) ? ptrU[u + 1] : nnz;
    float4 g4 = {0, 0, 0, 0}, s4 = {0, 0, 0, 0}, p4 = {0, 0, 0, 0};
    for (int k0 = start; k0 < end; k0 += 64) {
      int c_v = 0;
      float v_v = 0.f;
      const int kk = k0 + lane;
      if (kk < end) {
        const int2 e = csrU[kk];
        c_v = e.x;
        v_v = __int_as_float(e.y);
      }
      const int steps = (min(64, end - k0) + 3) >> 2;
      for (int t = 0; t < steps; ++t) {
        const int src = t * 4 + sub;
        const int cc = __shfl(c_v, src);
        const float vv = __shfl(v_v, src);
        const size_t rb = (size_t)cc * EDIM;
        const uint2 gg = ((const uint2*)(tblG + rb))[d4];
        const uint2 ss = ((const uint2*)(tblS + rb))[d4];
        const uint2 pp = ((const uint2*)(tblC + rb))[d4];
        g4.x += vv * bflo(gg.x); g4.y += vv * bfhi(gg.x);
        g4.z += vv * bflo(gg.y); g4.w += vv * bfhi(gg.y);
        s4.x += vv * bflo(ss.x); s4.y += vv * bfhi(ss.x);
        s4.z += vv * bflo(ss.y); s4.w += vv * bfhi(ss.y);
        p4.x += vv * bflo(pp.x); p4.y += vv * bfhi(pp.x);
        p4.z += vv * bflo(pp.y); p4.w += vv * bfhi(pp.y);
      }
    }
#pragma unroll
    for (int m = 16; m <= 32; m <<= 1) {
      g4.x += __shfl_xor(g4.x, m); g4.y += __shfl_xor(g4.y, m);
      g4.z += __shfl_xor(g4.z, m); g4.w += __shfl_xor(g4.w, m);
      s4.x += __shfl_xor(s4.x, m); s4.y += __shfl_xor(s4.y, m);
      s4.z += __shfl_xor(s4.z, m); s4.w += __shfl_xor(s4.w, m);
      p4.x += __shfl_xor(p4.x, m); p4.y += __shfl_xor(p4.y, m);
      p4.z += __shfl_xor(p4.z, m); p4.w += __shfl_xor(p4.w, m);
    }
    if (sub == 0) {
      uint2 gp2, sp2, pp2;
      gp2.x = f2bf(g4.x) | (f2bf(g4.y) << 16);
      gp2.y = f2bf(g4.z) | (f2bf(g4.w) << 16);
      sp2.x = f2bf(s4.x) | (f2bf(s4.y) << 16);
      sp2.y = f2bf(s4.z) | (f2bf(s4.w) << 16);
      pp2.x = f2bf(p4.x) | (f2bf(p4.y) << 16);
      pp2.y = f2bf(p4.z) | (f2bf(p4.w) << 16);
      ((uint2*)(gw + (size_t)u * EDIM))[d4] = gp2;
      ((uint2*)(sw + (size_t)u * EDIM))[d4] = sp2;
      ((uint2*)(pw + (size_t)u * EDIM))[d4] = pp2;
    }
  }
}

// ---------------------------------------------------------------------------
// Fusion as bf16 MFMA GEMM: msg[U,448] @ W^T[448,64] + bias + gated merge.
// Outputs hg as bf16.
// ---------------------------------------------------------------------------
#define FM_BLK 256
__global__ __launch_bounds__(FM_BLK) void fusion_mfma_kernel(
    const unsigned short* __restrict__ gbf, const unsigned short* __restrict__ sbf,
    const unsigned short* __restrict__ pbf, const float* __restrict__ uemb,
    const float* __restrict__ W, const float* __restrict__ b,
    unsigned short* __restrict__ hbf, int U) {
  __shared__ unsigned short wlds[7 * 2 * 4 * 64 * 8];  // 57344 B
  for (int fe = threadIdx.x; fe < 7 * 2 * 4 * 64; fe += FM_BLK) {
    const int ln = fe & 63;
    const int n = (fe >> 6) & 3;
    const int h = (fe >> 8) & 1;
    const int blk = fe >> 9;
    const int e = n * 16 + (ln & 15);
    const int f0 = blk * 64 + h * 32 + (ln >> 4) * 8;
    const float* wsrc = W + (size_t)e * 448 + f0;
    uint4 w4;
    w4.x = f2bf(wsrc[0]) | (f2bf(wsrc[1]) << 16);
    w4.y = f2bf(wsrc[2]) | (f2bf(wsrc[3]) << 16);
    w4.z = f2bf(wsrc[4]) | (f2bf(wsrc[5]) << 16);
    w4.w = f2bf(wsrc[6]) | (f2bf(wsrc[7]) << 16);
    ((uint4*)wlds)[fe] = w4;
  }
  __syncthreads();

  const int l = threadIdx.x & 63;
  const int row16 = l & 15, kg = l >> 4;
  const int wv = blockIdx.x * (FM_BLK / 64) + (threadIdx.x >> 6);
  const int nWv = gridDim.x * (FM_BLK / 64);
  float bias4[4];
#pragma unroll
  for (int n = 0; n < 4; ++n) bias4[n] = b[n * 16 + row16];

  const int nT = (U + 15) >> 4;
  for (int t = wv; t < nT; t += nWv) {
    const int u0 = t * 16;
    f32x4 acc0 = {0, 0, 0, 0}, acc1 = {0, 0, 0, 0};
    f32x4 acc2 = {0, 0, 0, 0}, acc3 = {0, 0, 0, 0};
    const int ua = min(u0 + row16, U - 1);  // clamped A-row user
#pragma unroll
    for (int h = 0; h < 2; ++h) {
      const size_t off = (size_t)ua * EDIM + h * 32 + kg * 8;
      short8 gfr = *(const short8*)(gbf + off);
      short8 sfr = *(const short8*)(sbf + off);
      short8 pfr = *(const short8*)(pbf + off);
      float gf[8], sf[8], pf[8];
#pragma unroll
      for (int j = 0; j < 8; ++j) {
        gf[j] = bf2f((unsigned short)gfr[j]);
        sf[j] = bf2f((unsigned short)sfr[j]);
        pf[j] = bf2f((unsigned short)pfr[j]);
      }
      short8 gs, gp, sp, gsp;
#pragma unroll
      for (int j = 0; j < 8; ++j) {
        const float a = gf[j] * sf[j];
        gs[j] = (short)f2bf(a);
        gp[j] = (short)f2bf(gf[j] * pf[j]);
        sp[j] = (short)f2bf(sf[j] * pf[j]);
        gsp[j] = (short)f2bf(a * pf[j]);
      }
      short8 afr[7] = {gfr, sfr, pfr, gs, gp, sp, gsp};
#pragma unroll
      for (int blk = 0; blk < 7; ++blk) {
        const int fb = blk * 512 + h * 256;
        const short8 b0 = *(const short8*)(wlds + (size_t)(fb + 0 * 64 + l) * 8);
        const short8 b1 = *(const short8*)(wlds + (size_t)(fb + 1 * 64 + l) * 8);
        const short8 b2 = *(const short8*)(wlds + (size_t)(fb + 2 * 64 + l) * 8);
        const short8 b3 = *(const short8*)(wlds + (size_t)(fb + 3 * 64 + l) * 8);
        acc0 = __builtin_amdgcn_mfma_f32_16x16x32_bf16(afr[blk], b0, acc0, 0, 0, 0);
        acc1 = __builtin_amdgcn_mfma_f32_16x16x32_bf16(afr[blk], b1, acc1, 0, 0, 0);
        acc2 = __builtin_amdgcn_mfma_f32_16x16x32_bf16(afr[blk], b2, acc2, 0, 0, 0);
        acc3 = __builtin_amdgcn_mfma_f32_16x16x32_bf16(afr[blk], b3, acc3, 0, 0, 0);
      }
    }
    // epilogue: me = acc + bias; hg = me + ue + me*ue  (bf16 out)
#pragma unroll
    for (int r = 0; r < 4; ++r) {
      const int u = u0 + kg * 4 + r;
      if (u < U) {
        const size_t ubase = (size_t)u * EDIM + row16;
        {
          const float me = acc0[r] + bias4[0];
          const float ue = uemb[ubase + 0];
          hbf[ubase + 0] = (unsigned short)f2bf(me + ue + me * ue);
        }
        {
          const float me = acc1[r] + bias4[1];
          const float ue = uemb[ubase + 16];
          hbf[ubase + 16] = (unsigned short)f2bf(me + ue + me * ue);
        }
        {
          const float me = acc2[r] + bias4[2];
          const float ue = uemb[ubase + 32];
          hbf[ubase + 32] = (unsigned short)f2bf(me + ue + me * ue);
        }
        {
          const float me = acc3[r] + bias4[3];
          const float ue = uemb[ubase + 48];
          hbf[ubase + 48] = (unsigned short)f2bf(me + ue + me * ue);
        }
      }
    }
  }
}

// ---------------------------------------------------------------------------
// Per-POI gather over bf16 hg, direct csrP = {row, pu_val}, fused mean:
// out = init + (L/2)*acc.
// ---------------------------------------------------------------------------
__global__ __launch_bounds__(256) void poi_gather_kernel(
    const int* __restrict__ ptrP, const int2* __restrict__ csrP,
    const unsigned short* __restrict__ hbf, const float* __restrict__ init,
    const int* __restrict__ num_layers, float* __restrict__ out, int P,
    int nnz) {
  const float scale = 0.5f * (float)num_layers[0];
  const int lane = threadIdx.x & 63;
  const int sub = lane >> 4, d4 = lane & 15;
  const int wv = blockIdx.x * 4 + (threadIdx.x >> 6);
  const int nW = gridDim.x * 4;
  for (int c = wv; c < P; c += nW) {
    const int start = ptrP[c];
    const int end = (c + 1 < P) ? ptrP[c + 1] : nnz;
    float4 a4 = {0, 0, 0, 0};
    for (int k0 = start; k0 < end; k0 += 64) {
      int r_v = 0;
      float v_v = 0.f;
      const int kk = k0 + lane;
      if (kk < end) {
        const int2 e = csrP[kk];
        r_v = e.x;
        v_v = __int_as_float(e.y);
      }
      const int steps = (min(64, end - k0) + 3) >> 2;
      for (int t = 0; t < steps; ++t) {
        const int src = t * 4 + sub;
        const int rr = __shfl(r_v, src);
        const float vv = __shfl(v_v, src);
        const uint2 hh = ((const uint2*)(hbf + (size_t)rr * EDIM))[d4];
        a4.x += vv * bflo(hh.x); a4.y += vv * bfhi(hh.x);
        a4.z += vv * bflo(hh.y); a4.w += vv * bfhi(hh.y);
      }
    }
#pragma unroll
    for (int m = 16; m <= 32; m <<= 1) {
      a4.x += __shfl_xor(a4.x, m); a4.y += __shfl_xor(a4.y, m);
      a4.z += __shfl_xor(a4.z, m); a4.w += __shfl_xor(a4.w, m);
    }
    if (sub == 0) {
      const float4 iv = ((const float4*)(init + (size_t)c * EDIM))[d4];
      float4 o;
      o.x = iv.x + scale * a4.x;
      o.y = iv.y + scale * a4.y;
      o.z = iv.z + scale * a4.z;
      o.w = iv.w + scale * a4.w;
      ((float4*)(out + (size_t)c * EDIM))[d4] = o;
    }
  }
}

extern "C" void kernel_launch(void* const* d_in, const int* in_sizes, int n_in,
                              void* d_out, int out_size, void* d_ws,
                              size_t ws_size, hipStream_t stream) {
  const float* init = (const float*)d_in[0];
  const float* colp = (const float*)d_in[1];
  const float* geo = (const float*)d_in[2];
  const float* seq = (const float*)d_in[3];
  const float* uemb = (const float*)d_in[4];
  const int* up_rows = (const int*)d_in[5];
  const int* up_cols = (const int*)d_in[6];
  const float* up_vals = (const float*)d_in[7];
  const float* pu_vals = (const float*)d_in[8];
  const float* W = (const float*)d_in[9];
  const float* b = (const float*)d_in[10];
  const int* num_layers = (const int*)d_in[11];

  const int U = in_sizes[4] / EDIM;
  const int P = in_sizes[0] / EDIM;
  const int NNZ = in_sizes[5];

  // ---- workspace layout (peak ~102.0 MB) ----
  int* cntU4 = (int*)d_ws;                    // U*4 padded counters (1.6 MB)
  int* cntP4 = cntU4 + (size_t)U * CSTRIDE;   // P*4 padded counters (3.2 MB)
  int* ptrU = cntP4 + (size_t)P * CSTRIDE;    // U compact offsets
  int* ptrP = ptrU + U;                       // P
  int* bsumU = ptrP + P;                      // 256
  int* bsumP = bsumU + 256;                   // 256
  int2* csrU = (int2*)(bsumP + 256);          // NNZ {col, up_val}
  int2* csrP = csrU + NNZ;                    // NNZ {row, pu_val}
  unsigned short* tblS = (unsigned short*)(csrP + NNZ);  // P*64 bf16 (25.6 MB)
  unsigned short* hbf = tblS;                 // U*64 bf16, aliases tblS (dead)
  unsigned short* gbf = tblS + (size_t)P * EDIM;         // U*64 bf16
  unsigned short* sbf = gbf + (size_t)U * EDIM;
  unsigned short* pbf = sbf + (size_t)U * EDIM;
  int* rankU = (int*)gbf;                     // NNZ, aliases gbf/sbf (dead
  int* rankP = rankU + NNZ;                   //   before user_gather writes)
  // d_out doubles as scratch for two bf16 tables (dead before final write)
  unsigned short* tblG = (unsigned short*)d_out;          // P*64 bf16
  unsigned short* tblC = tblG + (size_t)P * EDIM;         // P*64 bf16
  float* out = (float*)d_out;

  const int nbU = (U + SCAN_CHUNK - 1) / SCAN_CHUNK;
  const int nbP = (P + SCAN_CHUNK - 1) / SCAN_CHUNK;
  const int nb4 = (NNZ / 4 + 255) / 256 + 1;  // threads of 4 nnz each (+tail)

  hipMemsetAsync(cntU4, 0, (size_t)(U + P) * CSTRIDE * sizeof(int), stream);

  tobf16_kernel<<<2048, 256, 0, stream>>>(
      (const float4*)geo, (const float4*)seq, (const float4*)colp,
      (uint2*)tblG, (uint2*)tblS, (uint2*)tblC, P * (EDIM / 4));

  hist_rank_kernel<<<nb4, 256, 0, stream>>>(up_rows, up_cols, cntU4, cntP4,
                                            rankU, rankP, NNZ);

  scan_reduce_kernel<<<nbU, SCAN_BLK, 0, stream>>>(cntU4, U, bsumU);
  scan_reduce_kernel<<<nbP, SCAN_BLK, 0, stream>>>(cntP4, P, bsumP);
  scan_top_kernel<<<1, 256, 0, stream>>>(bsumU, nbU);
  scan_top_kernel<<<1, 256, 0, stream>>>(bsumP, nbP);
  scan_apply_kernel<<<nbU, SCAN_BLK, 0, stream>>>(cntU4, ptrU, U, bsumU);
  scan_apply_kernel<<<nbP, SCAN_BLK, 0, stream>>>(cntP4, ptrP, P, bsumP);

  scatter_kernel<<<nb4, 256, 0, stream>>>(up_rows, up_cols, up_vals, pu_vals,
                                          ptrU, ptrP, rankU, rankP, csrU,
                                          csrP, NNZ);

  user_gather_kernel<<<2048, 256, 0, stream>>>(ptrU, csrU, tblG, tblS, tblC,
                                               gbf, sbf, pbf, U, NNZ);

  fusion_mfma_kernel<<<512, FM_BLK, 0, stream>>>(gbf, sbf, pbf, uemb, W, b,
                                                 hbf, U);

  poi_gather_kernel<<<2048, 256, 0, stream>>>(ptrP, csrP, hbf, init,
                                              num_layers, out, P, NNZ);
}

// Round 10
// 478.921 us; speedup vs baseline: 2.6963x; 1.1471x over previous
//
#include <hip/hip_runtime.h>

#define EDIM 64
#define RCAP 8192    // per-bucket region capacity (mean ~5115, +43 sigma)
#define NBMAX 512

typedef __attribute__((ext_vector_type(8))) short short8;
typedef __attribute__((ext_vector_type(4))) float f32x4;

// f32 -> bf16 round-to-nearest-even
__device__ __forceinline__ unsigned int f2bf(float x) {
  unsigned int u = __float_as_uint(x);
  u += 0x7FFFu + ((u >> 16) & 1u);
  return u >> 16;
}
__device__ __forceinline__ float bf2f(unsigned short s) {
  return __uint_as_float(((unsigned int)s) << 16);
}
__device__ __forceinline__ float bflo(unsigned int u) {
  return __uint_as_float(u << 16);
}
__device__ __forceinline__ float bfhi(unsigned int u) {
  return __uint_as_float(u & 0xFFFF0000u);
}

// ---------------------------------------------------------------------------
// f32 -> bf16 table conversion (3 tables in one launch).
// ---------------------------------------------------------------------------
__global__ __launch_bounds__(256) void tobf16_kernel(
    const float4* __restrict__ s0, const float4* __restrict__ s1,
    const float4* __restrict__ s2, uint2* __restrict__ d0,
    uint2* __restrict__ d1, uint2* __restrict__ d2, int n4) {
  const int stride = gridDim.x * blockDim.x;
  for (int i = blockIdx.x * blockDim.x + threadIdx.x; i < 3 * n4; i += stride) {
    const int t = i / n4, j = i - t * n4;
    const float4* s = (t == 0) ? s0 : ((t == 1) ? s1 : s2);
    uint2* d = (t == 0) ? d0 : ((t == 1) ? d1 : d2);
    const float4 v = s[j];
    uint2 o;
    o.x = f2bf(v.x) | (f2bf(v.y) << 16);
    o.y = f2bf(v.z) | (f2bf(v.w) << 16);
    d[j] = o;
  }
}

// ---------------------------------------------------------------------------
// Bucket pass 1: LDS bucket histogram, one global atomic per (block,bucket)
// to reserve a range, then scatter packed payloads into per-bucket regions.
// Payload word0 = p1 | (in-bucket key delta << 18); p1 < 2^18, delta < 2^9.
// ---------------------------------------------------------------------------
__global__ __launch_bounds__(256) void bucket_pass1_kernel(
    const int* __restrict__ keys, const int* __restrict__ p1,
    const float* __restrict__ p2, int* __restrict__ gCursor,
    int2* __restrict__ regionPay, int nnz, int sh, int nb) {
  __shared__ int cnt[NBMAX];
  __shared__ int curs[NBMAX];
  const int tid = threadIdx.x;
  for (int i = tid; i < nb; i += 256) cnt[i] = 0;
  __syncthreads();
  const int chunk = (nnz + gridDim.x - 1) / gridDim.x;
  const int s = blockIdx.x * chunk;
  const int e = min(nnz, s + chunk);
  for (int i = s + tid; i < e; i += 256) atomicAdd(&cnt[keys[i] >> sh], 1);
  __syncthreads();
  for (int i = tid; i < nb; i += 256) {
    const int c = cnt[i];
    curs[i] = c ? atomicAdd(&gCursor[i], c) : 0;
  }
  __syncthreads();
  const int mask = (1 << sh) - 1;
  for (int i = s + tid; i < e; i += 256) {
    const int k = keys[i];
    const int b = k >> sh;
    const int pos = atomicAdd(&curs[b], 1);
    if (pos < RCAP) {
      regionPay[(b << 13) + pos] =
          make_int2(p1[i] | ((k & mask) << 18), __float_as_int(p2[i]));
    }
  }
}

// ---------------------------------------------------------------------------
// Exclusive scan of bucket totals -> csrBase (nb <= 512, trivial).
// ---------------------------------------------------------------------------
__global__ void bucket_scan_kernel(const int* __restrict__ cnt,
                                   int* __restrict__ base, int nb) {
  if (threadIdx.x == 0) {
    int run = 0;
    for (int i = 0; i < nb; ++i) {
      base[i] = run;
      run += cnt[i];
    }
  }
}

// ---------------------------------------------------------------------------
// Bucket pass 2: per-bucket LDS key histogram + scan -> compact ptr[] and
// final CSR payload scatter (contiguous per-bucket output range).
// ---------------------------------------------------------------------------
__global__ __launch_bounds__(256) void bucket_pass2_kernel(
    const int* __restrict__ gCursor, const int* __restrict__ csrBase,
    const int2* __restrict__ regionPay, int* __restrict__ ptr,
    int2* __restrict__ csr, int nkey, int sh, int kpb) {
  __shared__ int hist[NBMAX];
  const int b = blockIdx.x;
  const int tid = threadIdx.x;
  const int n = min(gCursor[b], RCAP);
  const int rb = b << 13;
  const int cb = csrBase[b];
  const int keyLo = b << sh;
  for (int i = tid; i < kpb; i += 256) hist[i] = 0;
  __syncthreads();
  for (int i = tid; i < n; i += 256)
    atomicAdd(&hist[(unsigned)regionPay[rb + i].x >> 18], 1);
  __syncthreads();
  if (tid == 0) {
    int run = 0;
    for (int k = 0; k < kpb; ++k) {
      const int c = hist[k];
      hist[k] = run;
      run += c;
    }
  }
  __syncthreads();
  for (int k = tid; k < kpb; k += 256) {
    const int key = keyLo + k;
    if (key < nkey) ptr[key] = cb + hist[k];
  }
  __syncthreads();
  for (int i = tid; i < n; i += 256) {
    const int2 e = regionPay[rb + i];
    const int k = (unsigned)e.x >> 18;
    const int pos = atomicAdd(&hist[k], 1);
    csr[cb + pos] = make_int2(e.x & 0x3FFFF, e.y);
  }
}

// ---------------------------------------------------------------------------
// Per-user gather over bf16 tables -> bf16 g/s/p outputs [U][64].
// ---------------------------------------------------------------------------
__global__ __launch_bounds__(256) void user_gather_kernel(
    const int* __restrict__ ptrU, const int2* __restrict__ csrU,
    const unsigned short* __restrict__ tblG,
    const unsigned short* __restrict__ tblS,
    const unsigned short* __restrict__ tblC,
    unsigned short* __restrict__ gw, unsigned short* __restrict__ sw,
    unsigned short* __restrict__ pw, int U, int nnz) {
  const int lane = threadIdx.x & 63;
  const int sub = lane >> 4, d4 = lane & 15;
  const int wv = blockIdx.x * 4 + (threadIdx.x >> 6);
  const int nW = gridDim.x * 4;
  for (int u = wv; u < U; u += nW) {
    const int start = ptrU[u];
    const int end = (u + 1 < U) ? ptrU[u + 1] : nnz;
    float4 g4 = {0, 0, 0, 0}, s4 = {0, 0, 0, 0}, p4 = {0, 0, 0, 0};
    for (int k0 = start; k0 < end; k0 += 64) {
      int c_v = 0;
      float v_v = 0.f;
      const int kk = k0 + lane;
      if (kk < end) {
        const int2 e = csrU[kk];
        c_v = e.x;
        v_v = __int_as_float(e.y);
      }
      const int steps = (min(64, end - k0) + 3) >> 2;
      for (int t = 0; t < steps; ++t) {
        const int src = t * 4 + sub;
        const int cc = __shfl(c_v, src);
        const float vv = __shfl(v_v, src);
        const size_t rb = (size_t)cc * EDIM;
        const uint2 gg = ((const uint2*)(tblG + rb))[d4];
        const uint2 ss = ((const uint2*)(tblS + rb))[d4];
        const uint2 pp = ((const uint2*)(tblC + rb))[d4];
        g4.x += vv * bflo(gg.x); g4.y += vv * bfhi(gg.x);
        g4.z += vv * bflo(gg.y); g4.w += vv * bfhi(gg.y);
        s4.x += vv * bflo(ss.x); s4.y += vv * bfhi(ss.x);
        s4.z += vv * bflo(ss.y); s4.w += vv * bfhi(ss.y);
        p4.x += vv * bflo(pp.x); p4.y += vv * bfhi(pp.x);
        p4.z += vv * bflo(pp.y); p4.w += vv * bfhi(pp.y);
      }
    }
#pragma unroll
    for (int m = 16; m <= 32; m <<= 1) {
      g4.x += __shfl_xor(g4.x, m); g4.y += __shfl_xor(g4.y, m);
      g4.z += __shfl_xor(g4.z, m); g4.w += __shfl_xor(g4.w, m);
      s4.x += __shfl_xor(s4.x, m); s4.y += __shfl_xor(s4.y, m);
      s4.z += __shfl_xor(s4.z, m); s4.w += __shfl_xor(s4.w, m);
      p4.x += __shfl_xor(p4.x, m); p4.y += __shfl_xor(p4.y, m);
      p4.z += __shfl_xor(p4.z, m); p4.w += __shfl_xor(p4.w, m);
    }
    if (sub == 0) {
      uint2 gp2, sp2, pp2;
      gp2.x = f2bf(g4.x) | (f2bf(g4.y) << 16);
      gp2.y = f2bf(g4.z) | (f2bf(g4.w) << 16);
      sp2.x = f2bf(s4.x) | (f2bf(s4.y) << 16);
      sp2.y = f2bf(s4.z) | (f2bf(s4.w) << 16);
      pp2.x = f2bf(p4.x) | (f2bf(p4.y) << 16);
      pp2.y = f2bf(p4.z) | (f2bf(p4.w) << 16);
      ((uint2*)(gw + (size_t)u * EDIM))[d4] = gp2;
      ((uint2*)(sw + (size_t)u * EDIM))[d4] = sp2;
      ((uint2*)(pw + (size_t)u * EDIM))[d4] = pp2;
    }
  }
}

// ---------------------------------------------------------------------------
// Fusion as bf16 MFMA GEMM: msg[U,448] @ W^T[448,64] + bias + gated merge.
// ---------------------------------------------------------------------------
#define FM_BLK 256
__global__ __launch_bounds__(FM_BLK) void fusion_mfma_kernel(
    const unsigned short* __restrict__ gbf, const unsigned short* __restrict__ sbf,
    const unsigned short* __restrict__ pbf, const float* __restrict__ uemb,
    const float* __restrict__ W, const float* __restrict__ b,
    unsigned short* __restrict__ hbf, int U) {
  __shared__ unsigned short wlds[7 * 2 * 4 * 64 * 8];  // 57344 B
  for (int fe = threadIdx.x; fe < 7 * 2 * 4 * 64; fe += FM_BLK) {
    const int ln = fe & 63;
    const int n = (fe >> 6) & 3;
    const int h = (fe >> 8) & 1;
    const int blk = fe >> 9;
    const int e = n * 16 + (ln & 15);
    const int f0 = blk * 64 + h * 32 + (ln >> 4) * 8;
    const float* wsrc = W + (size_t)e * 448 + f0;
    uint4 w4;
    w4.x = f2bf(wsrc[0]) | (f2bf(wsrc[1]) << 16);
    w4.y = f2bf(wsrc[2]) | (f2bf(wsrc[3]) << 16);
    w4.z = f2bf(wsrc[4]) | (f2bf(wsrc[5]) << 16);
    w4.w = f2bf(wsrc[6]) | (f2bf(wsrc[7]) << 16);
    ((uint4*)wlds)[fe] = w4;
  }
  __syncthreads();

  const int l = threadIdx.x & 63;
  const int row16 = l & 15, kg = l >> 4;
  const int wv = blockIdx.x * (FM_BLK / 64) + (threadIdx.x >> 6);
  const int nWv = gridDim.x * (FM_BLK / 64);
  float bias4[4];
#pragma unroll
  for (int n = 0; n < 4; ++n) bias4[n] = b[n * 16 + row16];

  const int nT = (U + 15) >> 4;
  for (int t = wv; t < nT; t += nWv) {
    const int u0 = t * 16;
    f32x4 acc0 = {0, 0, 0, 0}, acc1 = {0, 0, 0, 0};
    f32x4 acc2 = {0, 0, 0, 0}, acc3 = {0, 0, 0, 0};
    const int ua = min(u0 + row16, U - 1);  // clamped A-row user
#pragma unroll
    for (int h = 0; h < 2; ++h) {
      const size_t off = (size_t)ua * EDIM + h * 32 + kg * 8;
      short8 gfr = *(const short8*)(gbf + off);
      short8 sfr = *(const short8*)(sbf + off);
      short8 pfr = *(const short8*)(pbf + off);
      float gf[8], sf[8], pf[8];
#pragma unroll
      for (int j = 0; j < 8; ++j) {
        gf[j] = bf2f((unsigned short)gfr[j]);
        sf[j] = bf2f((unsigned short)sfr[j]);
        pf[j] = bf2f((unsigned short)pfr[j]);
      }
      short8 gs, gp, sp, gsp;
#pragma unroll
      for (int j = 0; j < 8; ++j) {
        const float a = gf[j] * sf[j];
        gs[j] = (short)f2bf(a);
        gp[j] = (short)f2bf(gf[j] * pf[j]);
        sp[j] = (short)f2bf(sf[j] * pf[j]);
        gsp[j] = (short)f2bf(a * pf[j]);
      }
      short8 afr[7] = {gfr, sfr, pfr, gs, gp, sp, gsp};
#pragma unroll
      for (int blk = 0; blk < 7; ++blk) {
        const int fb = blk * 512 + h * 256;
        const short8 b0 = *(const short8*)(wlds + (size_t)(fb + 0 * 64 + l) * 8);
        const short8 b1 = *(const short8*)(wlds + (size_t)(fb + 1 * 64 + l) * 8);
        const short8 b2 = *(const short8*)(wlds + (size_t)(fb + 2 * 64 + l) * 8);
        const short8 b3 = *(const short8*)(wlds + (size_t)(fb + 3 * 64 + l) * 8);
        acc0 = __builtin_amdgcn_mfma_f32_16x16x32_bf16(afr[blk], b0, acc0, 0, 0, 0);
        acc1 = __builtin_amdgcn_mfma_f32_16x16x32_bf16(afr[blk], b1, acc1, 0, 0, 0);
        acc2 = __builtin_amdgcn_mfma_f32_16x16x32_bf16(afr[blk], b2, acc2, 0, 0, 0);
        acc3 = __builtin_amdgcn_mfma_f32_16x16x32_bf16(afr[blk], b3, acc3, 0, 0, 0);
      }
    }
#pragma unroll
    for (int r = 0; r < 4; ++r) {
      const int u = u0 + kg * 4 + r;
      if (u < U) {
        const size_t ubase = (size_t)u * EDIM + row16;
        {
          const float me = acc0[r] + bias4[0];
          const float ue = uemb[ubase + 0];
          hbf[ubase + 0] = (unsigned short)f2bf(me + ue + me * ue);
        }
        {
          const float me = acc1[r] + bias4[1];
          const float ue = uemb[ubase + 16];
          hbf[ubase + 16] = (unsigned short)f2bf(me + ue + me * ue);
        }
        {
          const float me = acc2[r] + bias4[2];
          const float ue = uemb[ubase + 32];
          hbf[ubase + 32] = (unsigned short)f2bf(me + ue + me * ue);
        }
        {
          const float me = acc3[r] + bias4[3];
          const float ue = uemb[ubase + 48];
          hbf[ubase + 48] = (unsigned short)f2bf(me + ue + me * ue);
        }
      }
    }
  }
}

// ---------------------------------------------------------------------------
// Per-POI gather over bf16 hg, csrP = {row, pu_val}, fused mean:
// out = init + (L/2)*acc.
// ---------------------------------------------------------------------------
__global__ __launch_bounds__(256) void poi_gather_kernel(
    const int* __restrict__ ptrP, const int2* __restrict__ csrP,
    const unsigned short* __restrict__ hbf, const float* __restrict__ init,
    const int* __restrict__ num_layers, float* __restrict__ out, int P,
    int nnz) {
  const float scale = 0.5f * (float)num_layers[0];
  const int lane = threadIdx.x & 63;
  const int sub = lane >> 4, d4 = lane & 15;
  const int wv = blockIdx.x * 4 + (threadIdx.x >> 6);
  const int nW = gridDim.x * 4;
  for (int c = wv; c < P; c += nW) {
    const int start = ptrP[c];
    const int end = (c + 1 < P) ? ptrP[c + 1] : nnz;
    float4 a4 = {0, 0, 0, 0};
    for (int k0 = start; k0 < end; k0 += 64) {
      int r_v = 0;
      float v_v = 0.f;
      const int kk = k0 + lane;
      if (kk < end) {
        const int2 e = csrP[kk];
        r_v = e.x;
        v_v = __int_as_float(e.y);
      }
      const int steps = (min(64, end - k0) + 3) >> 2;
      for (int t = 0; t < steps; ++t) {
        const int src = t * 4 + sub;
        const int rr = __shfl(r_v, src);
        const float vv = __shfl(v_v, src);
        const uint2 hh = ((const uint2*)(hbf + (size_t)rr * EDIM))[d4];
        a4.x += vv * bflo(hh.x); a4.y += vv * bfhi(hh.x);
        a4.z += vv * bflo(hh.y); a4.w += vv * bfhi(hh.y);
      }
    }
#pragma unroll
    for (int m = 16; m <= 32; m <<= 1) {
      a4.x += __shfl_xor(a4.x, m); a4.y += __shfl_xor(a4.y, m);
      a4.z += __shfl_xor(a4.z, m); a4.w += __shfl_xor(a4.w, m);
    }
    if (sub == 0) {
      const float4 iv = ((const float4*)(init + (size_t)c * EDIM))[d4];
      float4 o;
      o.x = iv.x + scale * a4.x;
      o.y = iv.y + scale * a4.y;
      o.z = iv.z + scale * a4.z;
      o.w = iv.w + scale * a4.w;
      ((float4*)(out + (size_t)c * EDIM))[d4] = o;
    }
  }
}

extern "C" void kernel_launch(void* const* d_in, const int* in_sizes, int n_in,
                              void* d_out, int out_size, void* d_ws,
                              size_t ws_size, hipStream_t stream) {
  const float* init = (const float*)d_in[0];
  const float* colp = (const float*)d_in[1];
  const float* geo = (const float*)d_in[2];
  const float* seq = (const float*)d_in[3];
  const float* uemb = (const float*)d_in[4];
  const int* up_rows = (const int*)d_in[5];
  const int* up_cols = (const int*)d_in[6];
  const float* up_vals = (const float*)d_in[7];
  const float* pu_vals = (const float*)d_in[8];
  const float* W = (const float*)d_in[9];
  const float* b = (const float*)d_in[10];
  const int* num_layers = (const int*)d_in[11];

  const int U = in_sizes[4] / EDIM;   // 100000 users
  const int P = in_sizes[0] / EDIM;   // 200000 POIs
  const int NNZ = in_sizes[5];

  const int SHU = 8, SHP = 9;                 // 256 users / 512 POIs per bucket
  const int NBU = (U + 255) >> 8;             // 391
  const int NBP = (P + 511) >> 9;             // 391

  // ---- workspace layout (~97 MB) ----
  int* ptrU = (int*)d_ws;                     // U (0.4 MB)
  int* ptrP = ptrU + U;                       // P (0.8 MB)
  int* curU = ptrP + P;                       // 512
  int* curP = curU + NBMAX;                   // 512
  int* baseU = curP + NBMAX;                  // 512
  int* baseP = baseU + NBMAX;                 // 512
  int2* csrP = (int2*)(baseP + NBMAX);        // NNZ {row, pu_val} (16 MB)
  int2* csrU = csrP + NNZ;                    // NNZ {col, up_val} (16 MB)
  unsigned short* tblS = (unsigned short*)(csrU + NNZ);  // P*64 bf16 (25.6 MB)
  unsigned short* gbf = tblS + (size_t)P * EDIM;         // U*64 bf16 (12.8 MB)
  unsigned short* sbf = gbf + (size_t)U * EDIM;          // 12.8 MB
  unsigned short* pbf = sbf + (size_t)U * EDIM;          // 12.8 MB
  // hbf (12.8 MB) overlays csrU (16 MB, dead after user_gather)
  unsigned short* hbf = (unsigned short*)csrU;
  // bucket regions (391*8192 int2 = 25.6 MB) overlay gbf..pbf (38.4 MB,
  // dead until user_gather writes them after pass2 is done)
  int2* regionPay = (int2*)gbf;
  // d_out scratch: two bf16 tables (dead before final out write)
  unsigned short* tblG = (unsigned short*)d_out;          // P*64
  unsigned short* tblC = tblG + (size_t)P * EDIM;         // P*64
  float* out = (float*)d_out;

  hipMemsetAsync(curU, 0, 2 * NBMAX * sizeof(int), stream);

  tobf16_kernel<<<2048, 256, 0, stream>>>(
      (const float4*)geo, (const float4*)seq, (const float4*)colp,
      (uint2*)tblG, (uint2*)tblS, (uint2*)tblC, P * (EDIM / 4));

  // U-side CSR build (sorted by user; payload {col, up_val})
  bucket_pass1_kernel<<<256, 256, 0, stream>>>(up_rows, up_cols, up_vals,
                                               curU, regionPay, NNZ, SHU,
                                               NBU);
  bucket_scan_kernel<<<1, 64, 0, stream>>>(curU, baseU, NBU);
  bucket_pass2_kernel<<<NBU, 256, 0, stream>>>(curU, baseU, regionPay, ptrU,
                                               csrU, U, SHU, 256);

  // P-side CSC build (sorted by POI; payload {row, pu_val})
  bucket_pass1_kernel<<<256, 256, 0, stream>>>(up_cols, up_rows, pu_vals,
                                               curP, regionPay, NNZ, SHP,
                                               NBP);
  bucket_scan_kernel<<<1, 64, 0, stream>>>(curP, baseP, NBP);
  bucket_pass2_kernel<<<NBP, 256, 0, stream>>>(curP, baseP, regionPay, ptrP,
                                               csrP, P, SHP, 512);

  user_gather_kernel<<<2048, 256, 0, stream>>>(ptrU, csrU, tblG, tblS, tblC,
                                               gbf, sbf, pbf, U, NNZ);

  fusion_mfma_kernel<<<512, FM_BLK, 0, stream>>>(gbf, sbf, pbf, uemb, W, b,
                                                 hbf, U);

  poi_gather_kernel<<<2048, 256, 0, stream>>>(ptrP, csrP, hbf, init,
                                              num_layers, out, P, NNZ);
}